// Round 1
// baseline (1363.298 us; speedup 1.0000x reference)
//
#include <hip/hip_runtime.h>
#include <hip/hip_bf16.h>

#define N_NODES 100000
#define N_EDGES 1600000
#define N_GRAPHS 512
#define HID 128
#define BN_EPS 1e-5f

// ---------------- CSR build ----------------

__global__ __launch_bounds__(256) void k_hist(const int* __restrict__ dst, int* __restrict__ deg, int E) {
    int e = blockIdx.x * blockDim.x + threadIdx.x;
    if (e < E) atomicAdd(&deg[dst[e]], 1);
}

__global__ __launch_bounds__(1024) void k_scan(const int* __restrict__ deg, int* __restrict__ off,
                                               int* __restrict__ cur, int N) {
    __shared__ int buf[1024];
    int tid = threadIdx.x;
    int carry = 0;
    const int CH = 4096;
    for (int base = 0; base < N; base += CH) {
        int i0 = base + tid * 4;
        int v0 = 0, v1 = 0, v2 = 0, v3 = 0;
        if (i0 + 3 < N) {
            int4 t = *(const int4*)&deg[i0];
            v0 = t.x; v1 = t.y; v2 = t.z; v3 = t.w;
        } else {
            if (i0 + 0 < N) v0 = deg[i0];
            if (i0 + 1 < N) v1 = deg[i0 + 1];
            if (i0 + 2 < N) v2 = deg[i0 + 2];
            if (i0 + 3 < N) v3 = deg[i0 + 3];
        }
        int s = v0 + v1 + v2 + v3;
        buf[tid] = s;
        __syncthreads();
        for (int st = 1; st < 1024; st <<= 1) {
            int t = (tid >= st) ? buf[tid - st] : 0;
            __syncthreads();
            buf[tid] += t;
            __syncthreads();
        }
        int incl = buf[tid];
        int excl = carry + incl - s;
        int e0 = excl, e1 = e0 + v0, e2 = e1 + v1, e3 = e2 + v2;
        if (i0 + 0 < N) { off[i0 + 0] = e0; cur[i0 + 0] = e0; }
        if (i0 + 1 < N) { off[i0 + 1] = e1; cur[i0 + 1] = e1; }
        if (i0 + 2 < N) { off[i0 + 2] = e2; cur[i0 + 2] = e2; }
        if (i0 + 3 < N) { off[i0 + 3] = e3; cur[i0 + 3] = e3; }
        int tot = buf[1023];
        __syncthreads();
        carry += tot;
    }
    if (tid == 0) off[N] = carry;
}

__global__ __launch_bounds__(256) void k_fill(const int* __restrict__ src, const int* __restrict__ dst,
                                              int* __restrict__ cur, int* __restrict__ srcs, int E) {
    int e = blockIdx.x * blockDim.x + threadIdx.x;
    if (e < E) {
        int p = atomicAdd(&cur[dst[e]], 1);
        srcs[p] = src[e];
    }
}

__global__ __launch_bounds__(256) void k_gcnt(const int* __restrict__ batch, int* __restrict__ gcnt, int N) {
    int i = blockIdx.x * blockDim.x + threadIdx.x;
    if (i < N) atomicAdd(&gcnt[batch[i]], 1);
}

// ---------------- aggregation: T[i] = X[i] + sum_{j in-edges} X[src_j] ----------------

__global__ __launch_bounds__(256) void k_agg(const float* __restrict__ X, float* __restrict__ T,
                                             const int* __restrict__ off, const int* __restrict__ srcs, int N) {
    int gid = blockIdx.x * blockDim.x + threadIdx.x;
    int w = gid >> 6;
    int lane = threadIdx.x & 63;
    if (w >= N) return;
    const float2* X2 = (const float2*)X;
    float2 acc = X2[(size_t)w * 64 + lane];
    int s = off[w], e = off[w + 1];
    for (int j = s; j < e; ++j) {
        int u = srcs[j];
        float2 v = X2[(size_t)u * 64 + lane];
        acc.x += v.x;
        acc.y += v.y;
    }
    ((float2*)T)[(size_t)w * 64 + lane] = acc;
}

// ---------------- [N,128] @ [128,128] + bias (+relu), in-place safe ----------------

template <bool RELU>
__global__ __launch_bounds__(256) void k_mlp(const float* __restrict__ in, float* __restrict__ out,
                                             const float* __restrict__ W, const float* __restrict__ bias, int N) {
    __shared__ float sA[32][128];
    __shared__ float sW[64][128];
    int tid = threadIdx.x;
    int r0 = blockIdx.x * 32;

    // stage 32 input rows
    for (int t = 0; t < 4; ++t) {
        int idx = tid + 256 * t;       // float4 index, 0..1023
        int r = idx >> 5;
        int c4 = idx & 31;
        float4 v = make_float4(0.f, 0.f, 0.f, 0.f);
        if (r0 + r < N) v = ((const float4*)in)[(size_t)(r0 + r) * 32 + c4];
        *((float4*)&sA[r][c4 * 4]) = v;
    }

    float acc[4][4];
#pragma unroll
    for (int i = 0; i < 4; ++i)
#pragma unroll
        for (int j = 0; j < 4; ++j) acc[i][j] = 0.f;

    int cg = tid & 31;   // col group (4 cols)
    int rg = tid >> 5;   // row group (4 rows), 0..7

    for (int kh = 0; kh < 2; ++kh) {
        __syncthreads();
        for (int t = 0; t < 8; ++t) {
            int idx = tid + 256 * t;   // float4 index, 0..2047
            int kr = idx >> 5;
            int c4 = idx & 31;
            *((float4*)&sW[kr][c4 * 4]) = ((const float4*)W)[(size_t)(kh * 64 + kr) * 32 + c4];
        }
        __syncthreads();
#pragma unroll 4
        for (int k = 0; k < 64; ++k) {
            float4 w = *((float4*)&sW[k][cg * 4]);
            float a0 = sA[rg * 4 + 0][kh * 64 + k];
            float a1 = sA[rg * 4 + 1][kh * 64 + k];
            float a2 = sA[rg * 4 + 2][kh * 64 + k];
            float a3 = sA[rg * 4 + 3][kh * 64 + k];
            acc[0][0] = fmaf(a0, w.x, acc[0][0]); acc[0][1] = fmaf(a0, w.y, acc[0][1]);
            acc[0][2] = fmaf(a0, w.z, acc[0][2]); acc[0][3] = fmaf(a0, w.w, acc[0][3]);
            acc[1][0] = fmaf(a1, w.x, acc[1][0]); acc[1][1] = fmaf(a1, w.y, acc[1][1]);
            acc[1][2] = fmaf(a1, w.z, acc[1][2]); acc[1][3] = fmaf(a1, w.w, acc[1][3]);
            acc[2][0] = fmaf(a2, w.x, acc[2][0]); acc[2][1] = fmaf(a2, w.y, acc[2][1]);
            acc[2][2] = fmaf(a2, w.z, acc[2][2]); acc[2][3] = fmaf(a2, w.w, acc[2][3]);
            acc[3][0] = fmaf(a3, w.x, acc[3][0]); acc[3][1] = fmaf(a3, w.y, acc[3][1]);
            acc[3][2] = fmaf(a3, w.z, acc[3][2]); acc[3][3] = fmaf(a3, w.w, acc[3][3]);
        }
    }

    float4 b4 = ((const float4*)bias)[cg];
#pragma unroll
    for (int i = 0; i < 4; ++i) {
        int r = r0 + rg * 4 + i;
        if (r < N) {
            float4 v;
            v.x = acc[i][0] + b4.x;
            v.y = acc[i][1] + b4.y;
            v.z = acc[i][2] + b4.z;
            v.w = acc[i][3] + b4.w;
            if (RELU) {
                v.x = fmaxf(v.x, 0.f); v.y = fmaxf(v.y, 0.f);
                v.z = fmaxf(v.z, 0.f); v.w = fmaxf(v.w, 0.f);
            }
            ((float4*)out)[(size_t)r * 32 + cg] = v;
        }
    }
}

// ---------------- BN statistics: per-channel sum & sumsq ----------------

__global__ __launch_bounds__(256) void k_stats(const float* __restrict__ h, float* __restrict__ stats, int N) {
    int c = threadIdx.x & 127;
    int half = threadIdx.x >> 7;
    float s1 = 0.f, s2 = 0.f;
    for (int r = blockIdx.x * 2 + half; r < N; r += gridDim.x * 2) {
        float v = h[(size_t)r * 128 + c];
        s1 += v;
        s2 += v * v;
    }
    __shared__ float red[256];
    red[threadIdx.x] = s1;
    __syncthreads();
    if (half == 0) atomicAdd(&stats[c], s1 + red[threadIdx.x + 128]);
    __syncthreads();
    red[threadIdx.x] = s2;
    __syncthreads();
    if (half == 0) atomicAdd(&stats[128 + c], s2 + red[threadIdx.x + 128]);
}

// ---------------- BN apply + ReLU (in place) + segmented mean-pool accumulate ----------------

__global__ __launch_bounds__(128) void k_bn_pool(float* __restrict__ h, const float* __restrict__ stats,
                                                 const float* __restrict__ gamma, const float* __restrict__ beta,
                                                 const int* __restrict__ batch, float* __restrict__ pool,
                                                 int loff, int N) {
    int c = threadIdx.x;
    const float invN = 1.0f / (float)N;
    float mean = stats[c] * invN;
    float var = stats[128 + c] * invN - mean * mean;
    float rstd = rsqrtf(var + BN_EPS);
    float gsc = gamma[c] * rstd;
    float bs = beta[c] - mean * gsc;

    int r0 = blockIdx.x * 64;
    int r1 = min(r0 + 64, N);
    float acc = 0.f;
    int curg = -1;
    for (int r = r0; r < r1; ++r) {
        float v = h[(size_t)r * 128 + c];
        float hv = fmaxf(fmaf(v, gsc, bs), 0.f);
        h[(size_t)r * 128 + c] = hv;
        int g = batch[r];
        if (g != curg) {
            if (curg >= 0) atomicAdd(&pool[(size_t)curg * 384 + loff + c], acc);
            curg = g;
            acc = hv;
        } else {
            acc += hv;
        }
    }
    if (curg >= 0) atomicAdd(&pool[(size_t)curg * 384 + loff + c], acc);
}

// ---------------- final linear + row L2-normalize ----------------

__global__ __launch_bounds__(128) void k_final(const float* __restrict__ pool, const int* __restrict__ gcnt,
                                               const float* __restrict__ Wl, const float* __restrict__ bl,
                                               float* __restrict__ out) {
    __shared__ float sh[384];
    __shared__ float red[128];
    int g = blockIdx.x;
    int tid = threadIdx.x;
    float inv = 1.0f / fmaxf((float)gcnt[g], 1.0f);
    for (int t = tid; t < 384; t += 128) sh[t] = pool[(size_t)g * 384 + t] * inv;
    __syncthreads();
    float acc = bl[tid];
    for (int k = 0; k < 384; ++k) acc = fmaf(sh[k], Wl[(size_t)k * 128 + tid], acc);
    red[tid] = acc * acc;
    __syncthreads();
    for (int s = 64; s > 0; s >>= 1) {
        if (tid < s) red[tid] += red[tid + s];
        __syncthreads();
    }
    float norm = sqrtf(red[0]);
    float scale = 1.0f / fmaxf(norm, 1e-12f);
    out[(size_t)g * 128 + tid] = acc * scale;
}

// ---------------- host ----------------

extern "C" void kernel_launch(void* const* d_in, const int* in_sizes, int n_in,
                              void* d_out, int out_size, void* d_ws, size_t ws_size,
                              hipStream_t stream) {
    const float* x = (const float*)d_in[0];
    const int* edge_index = (const int*)d_in[1];
    const int* batch = (const int*)d_in[2];
    const float* Wa[3] = {(const float*)d_in[3], (const float*)d_in[9], (const float*)d_in[15]};
    const float* ba[3] = {(const float*)d_in[4], (const float*)d_in[10], (const float*)d_in[16]};
    const float* Wb[3] = {(const float*)d_in[5], (const float*)d_in[11], (const float*)d_in[17]};
    const float* bb[3] = {(const float*)d_in[6], (const float*)d_in[12], (const float*)d_in[18]};
    const float* gm[3] = {(const float*)d_in[7], (const float*)d_in[13], (const float*)d_in[19]};
    const float* be[3] = {(const float*)d_in[8], (const float*)d_in[14], (const float*)d_in[20]};
    const float* Wl = (const float*)d_in[21];
    const float* bl = (const float*)d_in[22];
    float* out = (float*)d_out;

    const int N = N_NODES, E = N_EDGES, G = N_GRAPHS;
    const int* e_src = edge_index;
    const int* e_dst = edge_index + E;

    // workspace layout
    char* ws = (char*)d_ws;
    size_t o = 0;
    auto alloc = [&](size_t bytes) -> char* {
        char* p = ws + o;
        o = (o + bytes + 255) & ~(size_t)255;
        return p;
    };
    int* deg = (int*)alloc((size_t)N * 4);
    int* off = (int*)alloc((size_t)(N + 1) * 4);
    int* cur = (int*)alloc((size_t)N * 4);
    int* srcs = (int*)alloc((size_t)E * 4);
    int* gcnt = (int*)alloc((size_t)G * 4);
    float* stats = (float*)alloc(256 * 4);
    float* pool = (float*)alloc((size_t)G * 384 * 4);
    float* P = (float*)alloc((size_t)N * 128 * 4);
    float* Q = (float*)alloc((size_t)N * 128 * 4);
    (void)ws_size;

    hipMemsetAsync(deg, 0, (size_t)N * 4, stream);
    hipMemsetAsync(gcnt, 0, (size_t)G * 4, stream);
    hipMemsetAsync(pool, 0, (size_t)G * 384 * 4, stream);

    // CSR build (by destination)
    k_hist<<<(E + 255) / 256, 256, 0, stream>>>(e_dst, deg, E);
    k_scan<<<1, 1024, 0, stream>>>(deg, off, cur, N);
    k_fill<<<(E + 255) / 256, 256, 0, stream>>>(e_src, e_dst, cur, srcs, E);
    k_gcnt<<<(N + 255) / 256, 256, 0, stream>>>(batch, gcnt, N);

    const int aggBlocks = (N * 64 + 255) / 256;
    const int mmBlocks = (N + 31) / 32;
    const int bnBlocks = (N + 63) / 64;

    const float* X = x;
    float* bufs[3] = {P, Q, P};
    for (int l = 0; l < 3; ++l) {
        float* T = bufs[l];
        hipMemsetAsync(stats, 0, 256 * 4, stream);
        k_agg<<<aggBlocks, 256, 0, stream>>>(X, T, off, srcs, N);
        k_mlp<true><<<mmBlocks, 256, 0, stream>>>(T, T, Wa[l], ba[l], N);
        k_mlp<false><<<mmBlocks, 256, 0, stream>>>(T, T, Wb[l], bb[l], N);
        k_stats<<<512, 256, 0, stream>>>(T, stats, N);
        k_bn_pool<<<bnBlocks, 128, 0, stream>>>(T, stats, gm[l], be[l], batch, pool, l * 128, N);
        X = T;
    }

    k_final<<<G, 128, 0, stream>>>(pool, gcnt, Wl, bl, out);
}

// Round 2
// 1163.241 us; speedup vs baseline: 1.1720x; 1.1720x over previous
//
#include <hip/hip_runtime.h>
#include <hip/hip_bf16.h>

#define N_NODES 100000
#define N_EDGES 1600000
#define N_GRAPHS 512
#define BN_EPS 1e-5f

typedef float f32x4 __attribute__((ext_vector_type(4)));
typedef short s16x8 __attribute__((ext_vector_type(8)));

__device__ inline ushort f2bf(float f) {
    union { float f; unsigned u; } v; v.f = f;
    unsigned u = v.u;
    unsigned r = (u + 0x7FFFu + ((u >> 16) & 1u)) >> 16;
    return (ushort)r;
}
__device__ inline float bf2f(ushort h) {
    union { unsigned u; float f; } v; v.u = ((unsigned)h) << 16;
    return v.f;
}

// ---------------- CSR build ----------------

__global__ __launch_bounds__(256) void k_hist(const int* __restrict__ dst, int* __restrict__ deg, int E) {
    int e = blockIdx.x * blockDim.x + threadIdx.x;
    if (e < E) atomicAdd(&deg[dst[e]], 1);
}

__global__ __launch_bounds__(1024) void k_scan(const int* __restrict__ deg, int* __restrict__ off,
                                               int* __restrict__ cur, int N) {
    __shared__ int buf[1024];
    int tid = threadIdx.x;
    int carry = 0;
    const int CH = 4096;
    for (int base = 0; base < N; base += CH) {
        int i0 = base + tid * 4;
        int v0 = 0, v1 = 0, v2 = 0, v3 = 0;
        if (i0 + 3 < N) {
            int4 t = *(const int4*)&deg[i0];
            v0 = t.x; v1 = t.y; v2 = t.z; v3 = t.w;
        } else {
            if (i0 + 0 < N) v0 = deg[i0];
            if (i0 + 1 < N) v1 = deg[i0 + 1];
            if (i0 + 2 < N) v2 = deg[i0 + 2];
            if (i0 + 3 < N) v3 = deg[i0 + 3];
        }
        int s = v0 + v1 + v2 + v3;
        buf[tid] = s;
        __syncthreads();
        for (int st = 1; st < 1024; st <<= 1) {
            int t = (tid >= st) ? buf[tid - st] : 0;
            __syncthreads();
            buf[tid] += t;
            __syncthreads();
        }
        int incl = buf[tid];
        int excl = carry + incl - s;
        int e0 = excl, e1 = e0 + v0, e2 = e1 + v1, e3 = e2 + v2;
        if (i0 + 0 < N) { off[i0 + 0] = e0; cur[i0 + 0] = e0; }
        if (i0 + 1 < N) { off[i0 + 1] = e1; cur[i0 + 1] = e1; }
        if (i0 + 2 < N) { off[i0 + 2] = e2; cur[i0 + 2] = e2; }
        if (i0 + 3 < N) { off[i0 + 3] = e3; cur[i0 + 3] = e3; }
        int tot = buf[1023];
        __syncthreads();
        carry += tot;
    }
    if (tid == 0) off[N] = carry;
}

__global__ __launch_bounds__(256) void k_fill(const int* __restrict__ src, const int* __restrict__ dst,
                                              int* __restrict__ cur, int* __restrict__ srcs, int E) {
    int e = blockIdx.x * blockDim.x + threadIdx.x;
    if (e < E) {
        int p = atomicAdd(&cur[dst[e]], 1);
        srcs[p] = src[e];
    }
}

__global__ __launch_bounds__(256) void k_gcnt(const int* __restrict__ batch, int* __restrict__ gcnt, int N) {
    int i = blockIdx.x * blockDim.x + threadIdx.x;
    if (i < N) atomicAdd(&gcnt[batch[i]], 1);
}

// ---------------- weight pre-pack into MFMA fragment layout (bf16 hi/lo) ----------------
// packed index p = ((kc*8 + n)*64 + l)*8 + j  ->  W[kc*32 + (l>>4)*8 + j][n*16 + (l&15)]
// hi at pk[p], lo at pk[16384 + p]

__global__ __launch_bounds__(256) void k_packw(const float* __restrict__ W, ushort* __restrict__ pk) {
    int p = blockIdx.x * 256 + threadIdx.x;   // 0..16383
    int j = p & 7, l = (p >> 3) & 63, n = (p >> 9) & 7, kc = p >> 12;
    int row = kc * 32 + ((l >> 4) & 3) * 8 + j;
    int col = n * 16 + (l & 15);
    float wv = W[row * 128 + col];
    ushort hi = f2bf(wv);
    ushort lo = f2bf(wv - bf2f(hi));
    pk[p] = hi;
    pk[16384 + p] = lo;
}

// ---------------- aggregation (+ lazy BN/ReLU of input): T[i] = f(X[i]) + sum f(X[src]) ----------------
// float4 per lane, 2 nodes per wave, unroll 4.

template <bool HASBN>
__global__ __launch_bounds__(256) void k_agg_bn(const float* __restrict__ X, float* __restrict__ T,
        const int* __restrict__ off, const int* __restrict__ srcs,
        const float* __restrict__ stats, const float* __restrict__ gamma, const float* __restrict__ beta,
        int N) {
    int gid = blockIdx.x * 256 + threadIdx.x;
    int w = gid >> 6;
    int lane = threadIdx.x & 63;
    int half = lane >> 5;
    int c4 = lane & 31;
    int node = w * 2 + half;
    if (node >= N) return;

    float4 gA = make_float4(1.f, 1.f, 1.f, 1.f), bA = make_float4(0.f, 0.f, 0.f, 0.f);
    if (HASBN) {
        int c = c4 * 4;
        float invN = 1.0f / (float)N;
#pragma unroll
        for (int t = 0; t < 4; ++t) {
            float m = stats[c + t] * invN;
            float v = stats[128 + c + t] * invN - m * m;
            float r = rsqrtf(v + BN_EPS);
            float g = gamma[c + t] * r;
            float b = beta[c + t] - m * g;
            ((float*)&gA)[t] = g;
            ((float*)&bA)[t] = b;
        }
    }

    const float4* X4 = (const float4*)X;
    auto ldf = [&](int u) -> float4 {
        float4 v = X4[(size_t)u * 32 + c4];
        if (HASBN) {
            v.x = fmaxf(fmaf(v.x, gA.x, bA.x), 0.f);
            v.y = fmaxf(fmaf(v.y, gA.y, bA.y), 0.f);
            v.z = fmaxf(fmaf(v.z, gA.z, bA.z), 0.f);
            v.w = fmaxf(fmaf(v.w, gA.w, bA.w), 0.f);
        }
        return v;
    };

    float4 acc = ldf(node);
    int s = off[node], e = off[node + 1];
    int j = s;
    for (; j + 3 < e; j += 4) {
        int u0 = srcs[j], u1 = srcs[j + 1], u2 = srcs[j + 2], u3 = srcs[j + 3];
        float4 a = ldf(u0), b = ldf(u1), c = ldf(u2), d = ldf(u3);
        acc.x += (a.x + b.x) + (c.x + d.x);
        acc.y += (a.y + b.y) + (c.y + d.y);
        acc.z += (a.z + b.z) + (c.z + d.z);
        acc.w += (a.w + b.w) + (c.w + d.w);
    }
    for (; j < e; ++j) {
        float4 a = ldf(srcs[j]);
        acc.x += a.x; acc.y += a.y; acc.z += a.z; acc.w += a.w;
    }
    ((float4*)T)[(size_t)node * 32 + c4] = acc;
}

// ---------------- [N,128]@[128,128] via split-bf16 MFMA, in-place safe ----------------
// wave = 2 row-tiles of 16 rows (32 rows); block = 4 waves = 128 rows.

template <bool RELU>
__global__ __launch_bounds__(256, 3) void k_mlp_mfma(const float* __restrict__ A, float* __restrict__ out,
                                                     const ushort* __restrict__ pk, const float* __restrict__ bias,
                                                     int N) {
    int tid = threadIdx.x;
    int wid = tid >> 6, l = tid & 63;
    int lr = l & 15, lg = l >> 4;
    int r0 = blockIdx.x * 128 + wid * 32;

    f32x4 acc[2][8];
#pragma unroll
    for (int m = 0; m < 2; ++m)
#pragma unroll
        for (int n = 0; n < 8; ++n) acc[m][n] = (f32x4){0.f, 0.f, 0.f, 0.f};

    const f32x4* A4 = (const f32x4*)A;
    const s16x8* B8 = (const s16x8*)pk;

#pragma unroll
    for (int kc = 0; kc < 4; ++kc) {
        s16x8 ahi[2], alo[2];
#pragma unroll
        for (int m = 0; m < 2; ++m) {
            int row = r0 + m * 16 + lr;
            row = min(row, N - 1);
            f32x4 v0 = A4[(size_t)row * 32 + kc * 8 + lg * 2];
            f32x4 v1 = A4[(size_t)row * 32 + kc * 8 + lg * 2 + 1];
            float f[8] = {v0.x, v0.y, v0.z, v0.w, v1.x, v1.y, v1.z, v1.w};
#pragma unroll
            for (int j = 0; j < 8; ++j) {
                ushort hi = f2bf(f[j]);
                ahi[m][j] = (short)hi;
                alo[m][j] = (short)f2bf(f[j] - bf2f(hi));
            }
        }
#pragma unroll
        for (int n = 0; n < 8; ++n) {
            int fi = (kc * 8 + n) * 64 + l;
            s16x8 bhi = B8[fi];
            s16x8 blo = B8[2048 + fi];
#pragma unroll
            for (int m = 0; m < 2; ++m) {
                acc[m][n] = __builtin_amdgcn_mfma_f32_16x16x32_bf16(ahi[m], bhi, acc[m][n], 0, 0, 0);
                acc[m][n] = __builtin_amdgcn_mfma_f32_16x16x32_bf16(alo[m], bhi, acc[m][n], 0, 0, 0);
                acc[m][n] = __builtin_amdgcn_mfma_f32_16x16x32_bf16(ahi[m], blo, acc[m][n], 0, 0, 0);
            }
        }
    }

    // C/D layout: col = lane&15, row_in_tile = (lane>>4)*4 + reg
#pragma unroll
    for (int n = 0; n < 8; ++n) {
        float bv = bias[n * 16 + lr];
#pragma unroll
        for (int m = 0; m < 2; ++m) {
#pragma unroll
            for (int i = 0; i < 4; ++i) {
                int r = r0 + m * 16 + lg * 4 + i;
                if (r < N) {
                    float v = acc[m][n][i] + bv;
                    if (RELU) v = fmaxf(v, 0.f);
                    out[(size_t)r * 128 + n * 16 + lr] = v;
                }
            }
        }
    }
}

// ---------------- BN statistics: per-channel sum & sumsq ----------------

__global__ __launch_bounds__(256) void k_stats(const float* __restrict__ h, float* __restrict__ stats, int N) {
    int c = threadIdx.x & 127;
    int half = threadIdx.x >> 7;
    float s1 = 0.f, s2 = 0.f;
    for (int r = blockIdx.x * 2 + half; r < N; r += gridDim.x * 2) {
        float v = h[(size_t)r * 128 + c];
        s1 += v;
        s2 += v * v;
    }
    __shared__ float red[256];
    red[threadIdx.x] = s1;
    __syncthreads();
    if (half == 0) atomicAdd(&stats[c], s1 + red[threadIdx.x + 128]);
    __syncthreads();
    red[threadIdx.x] = s2;
    __syncthreads();
    if (half == 0) atomicAdd(&stats[128 + c], s2 + red[threadIdx.x + 128]);
}

// ---------------- segmented mean-pool accumulate of f(h) (read-only) ----------------

__global__ __launch_bounds__(128) void k_pool(const float* __restrict__ h, const float* __restrict__ stats,
                                              const float* __restrict__ gamma, const float* __restrict__ beta,
                                              const int* __restrict__ batch, float* __restrict__ pool,
                                              int loff, int N) {
    int c = threadIdx.x;
    const float invN = 1.0f / (float)N;
    float mean = stats[c] * invN;
    float var = stats[128 + c] * invN - mean * mean;
    float rstd = rsqrtf(var + BN_EPS);
    float gsc = gamma[c] * rstd;
    float bs = beta[c] - mean * gsc;

    int r0 = blockIdx.x * 64;
    int r1 = min(r0 + 64, N);
    float acc = 0.f;
    int curg = -1;
    for (int r = r0; r < r1; ++r) {
        float v = h[(size_t)r * 128 + c];
        float hv = fmaxf(fmaf(v, gsc, bs), 0.f);
        int g = batch[r];
        if (g != curg) {
            if (curg >= 0) atomicAdd(&pool[(size_t)curg * 384 + loff + c], acc);
            curg = g;
            acc = hv;
        } else {
            acc += hv;
        }
    }
    if (curg >= 0) atomicAdd(&pool[(size_t)curg * 384 + loff + c], acc);
}

// ---------------- final linear + row L2-normalize ----------------

__global__ __launch_bounds__(128) void k_final(const float* __restrict__ pool, const int* __restrict__ gcnt,
                                               const float* __restrict__ Wl, const float* __restrict__ bl,
                                               float* __restrict__ out) {
    __shared__ float sh[384];
    __shared__ float red[128];
    int g = blockIdx.x;
    int tid = threadIdx.x;
    float inv = 1.0f / fmaxf((float)gcnt[g], 1.0f);
    for (int t = tid; t < 384; t += 128) sh[t] = pool[(size_t)g * 384 + t] * inv;
    __syncthreads();
    float acc = bl[tid];
    for (int k = 0; k < 384; ++k) acc = fmaf(sh[k], Wl[(size_t)k * 128 + tid], acc);
    red[tid] = acc * acc;
    __syncthreads();
    for (int s = 64; s > 0; s >>= 1) {
        if (tid < s) red[tid] += red[tid + s];
        __syncthreads();
    }
    float norm = sqrtf(red[0]);
    float scale = 1.0f / fmaxf(norm, 1e-12f);
    out[(size_t)g * 128 + tid] = acc * scale;
}

// ---------------- host ----------------

extern "C" void kernel_launch(void* const* d_in, const int* in_sizes, int n_in,
                              void* d_out, int out_size, void* d_ws, size_t ws_size,
                              hipStream_t stream) {
    const float* x = (const float*)d_in[0];
    const int* edge_index = (const int*)d_in[1];
    const int* batch = (const int*)d_in[2];
    const float* Wa[3] = {(const float*)d_in[3], (const float*)d_in[9], (const float*)d_in[15]};
    const float* ba[3] = {(const float*)d_in[4], (const float*)d_in[10], (const float*)d_in[16]};
    const float* Wb[3] = {(const float*)d_in[5], (const float*)d_in[11], (const float*)d_in[17]};
    const float* bb[3] = {(const float*)d_in[6], (const float*)d_in[12], (const float*)d_in[18]};
    const float* gm[3] = {(const float*)d_in[7], (const float*)d_in[13], (const float*)d_in[19]};
    const float* be[3] = {(const float*)d_in[8], (const float*)d_in[14], (const float*)d_in[20]};
    const float* Wl = (const float*)d_in[21];
    const float* bl = (const float*)d_in[22];
    float* out = (float*)d_out;

    const int N = N_NODES, E = N_EDGES, G = N_GRAPHS;
    const int* e_src = edge_index;
    const int* e_dst = edge_index + E;

    char* ws = (char*)d_ws;
    size_t o = 0;
    auto alloc = [&](size_t bytes) -> char* {
        char* p = ws + o;
        o = (o + bytes + 255) & ~(size_t)255;
        return p;
    };
    int* deg = (int*)alloc((size_t)N * 4);
    int* off = (int*)alloc((size_t)(N + 1) * 4);
    int* cur = (int*)alloc((size_t)N * 4);
    int* srcs = (int*)alloc((size_t)E * 4);
    int* gcnt = (int*)alloc((size_t)G * 4);
    float* stats = (float*)alloc(3 * 256 * 4);          // per-layer sum/sumsq
    ushort* wpk = (ushort*)alloc(6 * 32768 * 2);        // packed hi/lo weights
    float* pool = (float*)alloc((size_t)G * 384 * 4);
    float* P = (float*)alloc((size_t)N * 128 * 4);
    float* Q = (float*)alloc((size_t)N * 128 * 4);
    (void)ws_size;

    hipMemsetAsync(deg, 0, (size_t)N * 4, stream);
    hipMemsetAsync(gcnt, 0, (size_t)G * 4, stream);
    hipMemsetAsync(stats, 0, 3 * 256 * 4, stream);
    hipMemsetAsync(pool, 0, (size_t)G * 384 * 4, stream);

    // CSR build (by destination)
    k_hist<<<(E + 255) / 256, 256, 0, stream>>>(e_dst, deg, E);
    k_scan<<<1, 1024, 0, stream>>>(deg, off, cur, N);
    k_fill<<<(E + 255) / 256, 256, 0, stream>>>(e_src, e_dst, cur, srcs, E);
    k_gcnt<<<(N + 255) / 256, 256, 0, stream>>>(batch, gcnt, N);

    // pack weights: order W1a,W1b,W2a,W2b,W3a,W3b
    const float* Wmm[6] = {Wa[0], Wb[0], Wa[1], Wb[1], Wa[2], Wb[2]};
    for (int m = 0; m < 6; ++m)
        k_packw<<<64, 256, 0, stream>>>(Wmm[m], wpk + (size_t)m * 32768);

    const int aggBlocks = (N * 32 + 255) / 256;
    const int mlpBlocks = (N + 127) / 128;
    const int poolBlocks = (N + 63) / 64;

    float* bufIn[3] = {(float*)x, P, Q};
    float* bufOut[3] = {P, Q, P};
    for (int l = 0; l < 3; ++l) {
        float* T = bufOut[l];
        float* statsl = stats + l * 256;
        if (l == 0)
            k_agg_bn<false><<<aggBlocks, 256, 0, stream>>>(bufIn[l], T, off, srcs, nullptr, nullptr, nullptr, N);
        else
            k_agg_bn<true><<<aggBlocks, 256, 0, stream>>>(bufIn[l], T, off, srcs, stats + (l - 1) * 256,
                                                          gm[l - 1], be[l - 1], N);
        k_mlp_mfma<true><<<mlpBlocks, 256, 0, stream>>>(T, T, wpk + (size_t)(2 * l) * 32768, ba[l], N);
        k_mlp_mfma<false><<<mlpBlocks, 256, 0, stream>>>(T, T, wpk + (size_t)(2 * l + 1) * 32768, bb[l], N);
        k_stats<<<512, 256, 0, stream>>>(T, statsl, N);
        k_pool<<<poolBlocks, 128, 0, stream>>>(T, statsl, gm[l], be[l], batch, pool, l * 128, N);
    }

    k_final<<<G, 128, 0, stream>>>(pool, gcnt, Wl, bl, out);
}

// Round 3
// 1077.594 us; speedup vs baseline: 1.2651x; 1.0795x over previous
//
#include <hip/hip_runtime.h>
#include <hip/hip_bf16.h>

#define N_NODES 100000
#define N_EDGES 1600000
#define N_GRAPHS 512
#define BN_EPS 1e-5f

typedef float f32x4 __attribute__((ext_vector_type(4)));
typedef short s16x8 __attribute__((ext_vector_type(8)));

__device__ inline ushort f2bf(float f) {
    union { float f; unsigned u; } v; v.f = f;
    unsigned u = v.u;
    unsigned r = (u + 0x7FFFu + ((u >> 16) & 1u)) >> 16;
    return (ushort)r;
}
__device__ inline float bf2f(ushort h) {
    union { unsigned u; float f; } v; v.u = ((unsigned)h) << 16;
    return v.f;
}

// ---------------- CSR build ----------------

__global__ __launch_bounds__(256) void k_hist4(const int4* __restrict__ dst4, int* __restrict__ deg, int E4) {
    int t = blockIdx.x * 256 + threadIdx.x;
    if (t < E4) {
        int4 d = dst4[t];
        atomicAdd(&deg[d.x], 1);
        atomicAdd(&deg[d.y], 1);
        atomicAdd(&deg[d.z], 1);
        atomicAdd(&deg[d.w], 1);
    }
}

// scan1: per-block inclusive scan of deg -> off (temp), block totals -> partials
__global__ __launch_bounds__(1024) void k_scan1(const int* __restrict__ deg, int* __restrict__ off,
                                                int* __restrict__ partials, int N) {
    __shared__ int buf[1024];
    int tid = threadIdx.x;
    int i = blockIdx.x * 1024 + tid;
    int v = (i < N) ? deg[i] : 0;
    buf[tid] = v;
    __syncthreads();
    for (int st = 1; st < 1024; st <<= 1) {
        int t = (tid >= st) ? buf[tid - st] : 0;
        __syncthreads();
        buf[tid] += t;
        __syncthreads();
    }
    if (i < N) off[i] = buf[tid];
    if (tid == 1023) partials[blockIdx.x] = buf[1023];
}

// scan2: serial exclusive scan of partials (tiny), writes off[N]=total
__global__ __launch_bounds__(64) void k_scan2(int* __restrict__ partials, int* __restrict__ base,
                                              int* __restrict__ off, int nb, int N) {
    if (threadIdx.x == 0) {
        int run = 0;
        for (int b = 0; b < nb; ++b) {
            base[b] = run;
            run += partials[b];
        }
        off[N] = run;
    }
}

// scan3: off[i] = base[b] + incl - deg[i]; cur[i] = off[i]
__global__ __launch_bounds__(1024) void k_scan3(const int* __restrict__ deg, int* __restrict__ off,
                                                const int* __restrict__ base, int* __restrict__ cur, int N) {
    int i = blockIdx.x * 1024 + threadIdx.x;
    if (i < N) {
        int v = base[blockIdx.x] + off[i] - deg[i];
        off[i] = v;
        cur[i] = v;
    }
}

__global__ __launch_bounds__(256) void k_fill4(const int4* __restrict__ src4, const int4* __restrict__ dst4,
                                               int* __restrict__ cur, int* __restrict__ srcs, int E4) {
    int t = blockIdx.x * 256 + threadIdx.x;
    if (t < E4) {
        int4 d = dst4[t];
        int4 s = src4[t];
        int p0 = atomicAdd(&cur[d.x], 1);
        int p1 = atomicAdd(&cur[d.y], 1);
        int p2 = atomicAdd(&cur[d.z], 1);
        int p3 = atomicAdd(&cur[d.w], 1);
        srcs[p0] = s.x;
        srcs[p1] = s.y;
        srcs[p2] = s.z;
        srcs[p3] = s.w;
    }
}

__global__ __launch_bounds__(256) void k_gcnt4(const int4* __restrict__ batch4, int* __restrict__ gcnt, int N4) {
    int t = blockIdx.x * 256 + threadIdx.x;
    if (t < N4) {
        int4 b = batch4[t];
        atomicAdd(&gcnt[b.x], 1);
        atomicAdd(&gcnt[b.y], 1);
        atomicAdd(&gcnt[b.z], 1);
        atomicAdd(&gcnt[b.w], 1);
    }
}

// ---------------- weight pre-pack into MFMA fragment layout (bf16 hi/lo) ----------------

__global__ __launch_bounds__(256) void k_packw(const float* __restrict__ W, ushort* __restrict__ pk) {
    int p = blockIdx.x * 256 + threadIdx.x;   // 0..16383
    int j = p & 7, l = (p >> 3) & 63, n = (p >> 9) & 7, kc = p >> 12;
    int row = kc * 32 + ((l >> 4) & 3) * 8 + j;
    int col = n * 16 + (l & 15);
    float wv = W[row * 128 + col];
    ushort hi = f2bf(wv);
    ushort lo = f2bf(wv - bf2f(hi));
    pk[p] = hi;
    pk[16384 + p] = lo;
}

// ---------------- aggregation (+ lazy BN/ReLU of input) ----------------

template <bool HASBN>
__global__ __launch_bounds__(256) void k_agg_bn(const float* __restrict__ X, float* __restrict__ T,
        const int* __restrict__ off, const int* __restrict__ srcs,
        const float* __restrict__ stats, const float* __restrict__ gamma, const float* __restrict__ beta,
        int N) {
    int gid = blockIdx.x * 256 + threadIdx.x;
    int w = gid >> 6;
    int lane = threadIdx.x & 63;
    int half = lane >> 5;
    int c4 = lane & 31;
    int node = w * 2 + half;
    if (node >= N) return;

    float4 gA = make_float4(1.f, 1.f, 1.f, 1.f), bA = make_float4(0.f, 0.f, 0.f, 0.f);
    if (HASBN) {
        int c = c4 * 4;
        float invN = 1.0f / (float)N;
#pragma unroll
        for (int t = 0; t < 4; ++t) {
            float m = stats[c + t] * invN;
            float v = stats[128 + c + t] * invN - m * m;
            float r = rsqrtf(v + BN_EPS);
            float g = gamma[c + t] * r;
            float b = beta[c + t] - m * g;
            ((float*)&gA)[t] = g;
            ((float*)&bA)[t] = b;
        }
    }

    const float4* X4 = (const float4*)X;
    auto ldf = [&](int u) -> float4 {
        float4 v = X4[(size_t)u * 32 + c4];
        if (HASBN) {
            v.x = fmaxf(fmaf(v.x, gA.x, bA.x), 0.f);
            v.y = fmaxf(fmaf(v.y, gA.y, bA.y), 0.f);
            v.z = fmaxf(fmaf(v.z, gA.z, bA.z), 0.f);
            v.w = fmaxf(fmaf(v.w, gA.w, bA.w), 0.f);
        }
        return v;
    };

    float4 acc = ldf(node);
    int s = off[node], e = off[node + 1];
    int j = s;
    for (; j + 7 < e; j += 8) {
        int u0 = srcs[j], u1 = srcs[j + 1], u2 = srcs[j + 2], u3 = srcs[j + 3];
        int u4 = srcs[j + 4], u5 = srcs[j + 5], u6 = srcs[j + 6], u7 = srcs[j + 7];
        float4 a = ldf(u0), b = ldf(u1), c = ldf(u2), d = ldf(u3);
        float4 p = ldf(u4), q = ldf(u5), r = ldf(u6), t = ldf(u7);
        acc.x += ((a.x + b.x) + (c.x + d.x)) + ((p.x + q.x) + (r.x + t.x));
        acc.y += ((a.y + b.y) + (c.y + d.y)) + ((p.y + q.y) + (r.y + t.y));
        acc.z += ((a.z + b.z) + (c.z + d.z)) + ((p.z + q.z) + (r.z + t.z));
        acc.w += ((a.w + b.w) + (c.w + d.w)) + ((p.w + q.w) + (r.w + t.w));
    }
    for (; j + 1 < e; j += 2) {
        float4 a = ldf(srcs[j]), b = ldf(srcs[j + 1]);
        acc.x += a.x + b.x; acc.y += a.y + b.y; acc.z += a.z + b.z; acc.w += a.w + b.w;
    }
    for (; j < e; ++j) {
        float4 a = ldf(srcs[j]);
        acc.x += a.x; acc.y += a.y; acc.z += a.z; acc.w += a.w;
    }
    ((float4*)T)[(size_t)node * 32 + c4] = acc;
}

// ---------------- [N,128]@[128,128] via split-bf16 MFMA, in-place safe ----------------
// wave = 2 row-tiles of 16 rows (32 rows); block = 4 waves = 128 rows.
// STATS: also accumulate per-channel sum/sumsq of output into stats[256] (pre-BN h).

template <bool RELU, bool STATS>
__global__ __launch_bounds__(256, 3) void k_mlp_mfma(const float* __restrict__ A, float* __restrict__ out,
                                                     const ushort* __restrict__ pk, const float* __restrict__ bias,
                                                     float* __restrict__ stats, int N) {
    int tid = threadIdx.x;
    int wid = tid >> 6, l = tid & 63;
    int lr = l & 15, lg = l >> 4;
    int r0 = blockIdx.x * 128 + wid * 32;

    f32x4 acc[2][8];
#pragma unroll
    for (int m = 0; m < 2; ++m)
#pragma unroll
        for (int n = 0; n < 8; ++n) acc[m][n] = (f32x4){0.f, 0.f, 0.f, 0.f};

    const f32x4* A4 = (const f32x4*)A;
    const s16x8* B8 = (const s16x8*)pk;

#pragma unroll
    for (int kc = 0; kc < 4; ++kc) {
        s16x8 ahi[2], alo[2];
#pragma unroll
        for (int m = 0; m < 2; ++m) {
            int row = r0 + m * 16 + lr;
            row = min(row, N - 1);
            f32x4 v0 = A4[(size_t)row * 32 + kc * 8 + lg * 2];
            f32x4 v1 = A4[(size_t)row * 32 + kc * 8 + lg * 2 + 1];
            float f[8] = {v0.x, v0.y, v0.z, v0.w, v1.x, v1.y, v1.z, v1.w};
#pragma unroll
            for (int j = 0; j < 8; ++j) {
                ushort hi = f2bf(f[j]);
                ahi[m][j] = (short)hi;
                alo[m][j] = (short)f2bf(f[j] - bf2f(hi));
            }
        }
#pragma unroll
        for (int n = 0; n < 8; ++n) {
            int fi = (kc * 8 + n) * 64 + l;
            s16x8 bhi = B8[fi];
            s16x8 blo = B8[2048 + fi];
#pragma unroll
            for (int m = 0; m < 2; ++m) {
                acc[m][n] = __builtin_amdgcn_mfma_f32_16x16x32_bf16(ahi[m], bhi, acc[m][n], 0, 0, 0);
                acc[m][n] = __builtin_amdgcn_mfma_f32_16x16x32_bf16(alo[m], bhi, acc[m][n], 0, 0, 0);
                acc[m][n] = __builtin_amdgcn_mfma_f32_16x16x32_bf16(ahi[m], blo, acc[m][n], 0, 0, 0);
            }
        }
    }

    __shared__ float ls[4][256];

    float s1[8], s2[8];
    if (STATS) {
#pragma unroll
        for (int n = 0; n < 8; ++n) { s1[n] = 0.f; s2[n] = 0.f; }
    }

    // C/D layout: col = lane&15, row_in_tile = (lane>>4)*4 + reg
#pragma unroll
    for (int n = 0; n < 8; ++n) {
        float bv = bias[n * 16 + lr];
#pragma unroll
        for (int m = 0; m < 2; ++m) {
#pragma unroll
            for (int i = 0; i < 4; ++i) {
                int r = r0 + m * 16 + lg * 4 + i;
                if (r < N) {
                    float v = acc[m][n][i] + bv;
                    if (RELU) v = fmaxf(v, 0.f);
                    if (STATS) { s1[n] += v; s2[n] += v * v; }
                    out[(size_t)r * 128 + n * 16 + lr] = v;
                }
            }
        }
    }

    if (STATS) {
#pragma unroll
        for (int n = 0; n < 8; ++n) {
            float a = s1[n], b = s2[n];
            a += __shfl_xor(a, 16, 64); a += __shfl_xor(a, 32, 64);
            b += __shfl_xor(b, 16, 64); b += __shfl_xor(b, 32, 64);
            if (lg == 0) {
                ls[wid][n * 16 + lr] = a;
                ls[wid][128 + n * 16 + lr] = b;
            }
        }
        __syncthreads();
        float t = ls[0][tid] + ls[1][tid] + ls[2][tid] + ls[3][tid];
        atomicAdd(&stats[tid], t);
    }
}

// ---------------- segmented mean-pool accumulate of f(h) (read-only) ----------------

__global__ __launch_bounds__(128) void k_pool(const float* __restrict__ h, const float* __restrict__ stats,
                                              const float* __restrict__ gamma, const float* __restrict__ beta,
                                              const int* __restrict__ batch, float* __restrict__ pool,
                                              int loff, int N) {
    int c = threadIdx.x;
    const float invN = 1.0f / (float)N;
    float mean = stats[c] * invN;
    float var = stats[128 + c] * invN - mean * mean;
    float rstd = rsqrtf(var + BN_EPS);
    float gsc = gamma[c] * rstd;
    float bs = beta[c] - mean * gsc;

    int r0 = blockIdx.x * 64;
    int r1 = min(r0 + 64, N);
    float acc = 0.f;
    int curg = -1;
    for (int r = r0; r < r1; ++r) {
        float v = h[(size_t)r * 128 + c];
        float hv = fmaxf(fmaf(v, gsc, bs), 0.f);
        int g = batch[r];
        if (g != curg) {
            if (curg >= 0) atomicAdd(&pool[(size_t)curg * 384 + loff + c], acc);
            curg = g;
            acc = hv;
        } else {
            acc += hv;
        }
    }
    if (curg >= 0) atomicAdd(&pool[(size_t)curg * 384 + loff + c], acc);
}

// ---------------- final linear + row L2-normalize ----------------

__global__ __launch_bounds__(128) void k_final(const float* __restrict__ pool, const int* __restrict__ gcnt,
                                               const float* __restrict__ Wl, const float* __restrict__ bl,
                                               float* __restrict__ out) {
    __shared__ float sh[384];
    __shared__ float red[128];
    int g = blockIdx.x;
    int tid = threadIdx.x;
    float inv = 1.0f / fmaxf((float)gcnt[g], 1.0f);
    for (int t = tid; t < 384; t += 128) sh[t] = pool[(size_t)g * 384 + t] * inv;
    __syncthreads();
    float acc = bl[tid];
    for (int k = 0; k < 384; ++k) acc = fmaf(sh[k], Wl[(size_t)k * 128 + tid], acc);
    red[tid] = acc * acc;
    __syncthreads();
    for (int s = 64; s > 0; s >>= 1) {
        if (tid < s) red[tid] += red[tid + s];
        __syncthreads();
    }
    float norm = sqrtf(red[0]);
    float scale = 1.0f / fmaxf(norm, 1e-12f);
    out[(size_t)g * 128 + tid] = acc * scale;
}

// ---------------- host ----------------

extern "C" void kernel_launch(void* const* d_in, const int* in_sizes, int n_in,
                              void* d_out, int out_size, void* d_ws, size_t ws_size,
                              hipStream_t stream) {
    const float* x = (const float*)d_in[0];
    const int* edge_index = (const int*)d_in[1];
    const int* batch = (const int*)d_in[2];
    const float* Wa[3] = {(const float*)d_in[3], (const float*)d_in[9], (const float*)d_in[15]};
    const float* ba[3] = {(const float*)d_in[4], (const float*)d_in[10], (const float*)d_in[16]};
    const float* Wb[3] = {(const float*)d_in[5], (const float*)d_in[11], (const float*)d_in[17]};
    const float* bb[3] = {(const float*)d_in[6], (const float*)d_in[12], (const float*)d_in[18]};
    const float* gm[3] = {(const float*)d_in[7], (const float*)d_in[13], (const float*)d_in[19]};
    const float* be[3] = {(const float*)d_in[8], (const float*)d_in[14], (const float*)d_in[20]};
    const float* Wl = (const float*)d_in[21];
    const float* bl = (const float*)d_in[22];
    float* out = (float*)d_out;

    const int N = N_NODES, E = N_EDGES, G = N_GRAPHS;
    const int* e_src = edge_index;
    const int* e_dst = edge_index + E;

    char* ws = (char*)d_ws;
    size_t o = 0;
    auto alloc = [&](size_t bytes) -> char* {
        char* p = ws + o;
        o = (o + bytes + 255) & ~(size_t)255;
        return p;
    };
    int* deg = (int*)alloc((size_t)N * 4);
    int* off = (int*)alloc((size_t)(N + 1) * 4);
    int* cur = (int*)alloc((size_t)N * 4);
    int* srcs = (int*)alloc((size_t)E * 4);
    int* gcnt = (int*)alloc((size_t)G * 4);
    int* partials = (int*)alloc(128 * 4);
    int* sbase = (int*)alloc(128 * 4);
    float* stats = (float*)alloc(3 * 256 * 4);
    ushort* wpk = (ushort*)alloc(6 * 32768 * 2);
    float* pool = (float*)alloc((size_t)G * 384 * 4);
    float* P = (float*)alloc((size_t)N * 128 * 4);
    float* Q = (float*)alloc((size_t)N * 128 * 4);
    (void)ws_size;

    hipMemsetAsync(deg, 0, (size_t)N * 4, stream);
    hipMemsetAsync(gcnt, 0, (size_t)G * 4, stream);
    hipMemsetAsync(stats, 0, 3 * 256 * 4, stream);
    hipMemsetAsync(pool, 0, (size_t)G * 384 * 4, stream);

    // CSR build (by destination)
    const int E4 = E / 4;   // 400000
    const int N4 = N / 4;   // 25000
    const int SCB = (N + 1023) / 1024;  // 98
    k_hist4<<<(E4 + 255) / 256, 256, 0, stream>>>((const int4*)e_dst, deg, E4);
    k_scan1<<<SCB, 1024, 0, stream>>>(deg, off, partials, N);
    k_scan2<<<1, 64, 0, stream>>>(partials, sbase, off, SCB, N);
    k_scan3<<<SCB, 1024, 0, stream>>>(deg, off, sbase, cur, N);
    k_fill4<<<(E4 + 255) / 256, 256, 0, stream>>>((const int4*)e_src, (const int4*)e_dst, cur, srcs, E4);
    k_gcnt4<<<(N4 + 255) / 256, 256, 0, stream>>>((const int4*)batch, gcnt, N4);

    // pack weights: order W1a,W1b,W2a,W2b,W3a,W3b
    const float* Wmm[6] = {Wa[0], Wb[0], Wa[1], Wb[1], Wa[2], Wb[2]};
    for (int m = 0; m < 6; ++m)
        k_packw<<<64, 256, 0, stream>>>(Wmm[m], wpk + (size_t)m * 32768);

    const int aggBlocks = (N * 32 + 255) / 256;
    const int mlpBlocks = (N + 127) / 128;
    const int poolBlocks = (N + 63) / 64;

    float* bufIn[3] = {(float*)x, P, Q};
    float* bufOut[3] = {P, Q, P};
    for (int l = 0; l < 3; ++l) {
        float* T = bufOut[l];
        float* statsl = stats + l * 256;
        if (l == 0)
            k_agg_bn<false><<<aggBlocks, 256, 0, stream>>>(bufIn[l], T, off, srcs, nullptr, nullptr, nullptr, N);
        else
            k_agg_bn<true><<<aggBlocks, 256, 0, stream>>>(bufIn[l], T, off, srcs, stats + (l - 1) * 256,
                                                          gm[l - 1], be[l - 1], N);
        k_mlp_mfma<true, false><<<mlpBlocks, 256, 0, stream>>>(T, T, wpk + (size_t)(2 * l) * 32768, ba[l], nullptr, N);
        k_mlp_mfma<false, true><<<mlpBlocks, 256, 0, stream>>>(T, T, wpk + (size_t)(2 * l + 1) * 32768, bb[l], statsl, N);
        k_pool<<<poolBlocks, 128, 0, stream>>>(T, statsl, gm[l], be[l], batch, pool, l * 128, N);
    }

    k_final<<<G, 128, 0, stream>>>(pool, gcnt, Wl, bl, out);
}

// Round 4
// 817.180 us; speedup vs baseline: 1.6683x; 1.3187x over previous
//
#include <hip/hip_runtime.h>
#include <hip/hip_bf16.h>

#define N_NODES 100000
#define N_EDGES 1600000
#define N_GRAPHS 512
#define BN_EPS 1e-5f
#define NBKT 196          // buckets of 512 nodes: dst>>9
#define PART_CHUNK 4096

typedef float f32x4 __attribute__((ext_vector_type(4)));
typedef short s16x8 __attribute__((ext_vector_type(8)));

__device__ inline ushort f2bf(float f) {
    union { float f; unsigned u; } v; v.f = f;
    unsigned u = v.u;
    unsigned r = (u + 0x7FFFu + ((u >> 16) & 1u)) >> 16;
    return (ushort)r;
}
__device__ inline float bf2f(ushort h) {
    union { unsigned u; float f; } v; v.u = ((unsigned)h) << 16;
    return v.f;
}

// ---------------- histogram (edge degrees) + graph counts, one launch ----------------

__global__ __launch_bounds__(256) void k_hist_gcnt(const int4* __restrict__ dst4, int* __restrict__ deg,
                                                   const int4* __restrict__ batch4, int* __restrict__ gcnt,
                                                   int E4, int N4, int HB) {
    int bid = blockIdx.x, tid = threadIdx.x;
    if (bid < HB) {
        int t = bid * 256 + tid;
        if (t < E4) {
            int4 d = dst4[t];
            atomicAdd(&deg[d.x], 1);
            atomicAdd(&deg[d.y], 1);
            atomicAdd(&deg[d.z], 1);
            atomicAdd(&deg[d.w], 1);
        }
    } else {
        int t = (bid - HB) * 256 + tid;
        if (t < N4) {
            int4 b = batch4[t];
            atomicAdd(&gcnt[b.x], 1);
            atomicAdd(&gcnt[b.y], 1);
            atomicAdd(&gcnt[b.z], 1);
            atomicAdd(&gcnt[b.w], 1);
        }
    }
}

// ---------------- hierarchical scan of deg -> off ----------------

__global__ __launch_bounds__(1024) void k_scan1(const int* __restrict__ deg, int* __restrict__ off,
                                                int* __restrict__ partials, int N) {
    __shared__ int buf[1024];
    int tid = threadIdx.x;
    int i = blockIdx.x * 1024 + tid;
    int v = (i < N) ? deg[i] : 0;
    buf[tid] = v;
    __syncthreads();
    for (int st = 1; st < 1024; st <<= 1) {
        int t = (tid >= st) ? buf[tid - st] : 0;
        __syncthreads();
        buf[tid] += t;
        __syncthreads();
    }
    if (i < N) off[i] = buf[tid];
    if (tid == 1023) partials[blockIdx.x] = buf[1023];
}

__global__ __launch_bounds__(64) void k_scan2(int* __restrict__ partials, int* __restrict__ base,
                                              int* __restrict__ off, int nb, int N) {
    if (threadIdx.x == 0) {
        int run = 0;
        for (int b = 0; b < nb; ++b) {
            base[b] = run;
            run += partials[b];
        }
        off[N] = run;
    }
}

__global__ __launch_bounds__(1024) void k_scan3(const int* __restrict__ deg, int* __restrict__ off,
                                                const int* __restrict__ base, int N) {
    int i = blockIdx.x * 1024 + threadIdx.x;
    if (i < N) off[i] = base[blockIdx.x] + off[i] - deg[i];
}

// ---------------- bucket cursor init ----------------

__global__ __launch_bounds__(64) void k_binit(const int* __restrict__ off, int* __restrict__ gcur, int N) {
    int b = blockIdx.x * 64 + threadIdx.x;
    if (b < NBKT) gcur[b] = off[min(b << 9, N)];
}

// ---------------- stage 1: partition edges into 196 coarse buckets ----------------
// writes packed records (dstLow9 << 17) | src  in bucket-grouped runs

__global__ __launch_bounds__(256) void k_part(const int* __restrict__ esrc, const int* __restrict__ edst,
                                              int* __restrict__ gcur, unsigned* __restrict__ ebuf, int E) {
    __shared__ int cnt[256], base[256], scn[256];
    __shared__ unsigned ebufL[PART_CHUNK];
    __shared__ int gposL[PART_CHUNK];
    int tid = threadIdx.x;
    int e0 = blockIdx.x * PART_CHUNK;
    int nv = min(PART_CHUNK, E - e0);
    int src[16], dst[16];
    cnt[tid] = 0;
    __syncthreads();
    const int4* s4 = (const int4*)(esrc + e0);
    const int4* d4 = (const int4*)(edst + e0);
    int n4 = nv >> 2;
#pragma unroll
    for (int t = 0; t < 4; ++t) {
        int i4 = t * 256 + tid;
        if (i4 < n4) {
            int4 s = s4[i4];
            int4 d = d4[i4];
            src[t * 4 + 0] = s.x; src[t * 4 + 1] = s.y; src[t * 4 + 2] = s.z; src[t * 4 + 3] = s.w;
            dst[t * 4 + 0] = d.x; dst[t * 4 + 1] = d.y; dst[t * 4 + 2] = d.z; dst[t * 4 + 3] = d.w;
            atomicAdd(&cnt[d.x >> 9], 1);
            atomicAdd(&cnt[d.y >> 9], 1);
            atomicAdd(&cnt[d.z >> 9], 1);
            atomicAdd(&cnt[d.w >> 9], 1);
        } else {
            dst[t * 4 + 0] = -1; dst[t * 4 + 1] = -1; dst[t * 4 + 2] = -1; dst[t * 4 + 3] = -1;
            src[t * 4 + 0] = 0; src[t * 4 + 1] = 0; src[t * 4 + 2] = 0; src[t * 4 + 3] = 0;
        }
    }
    __syncthreads();
    int c = cnt[tid];
    if (tid < NBKT) base[tid] = atomicAdd(&gcur[tid], c);
    scn[tid] = c;
    __syncthreads();
    for (int st = 1; st < 256; st <<= 1) {
        int t = (tid >= st) ? scn[tid - st] : 0;
        __syncthreads();
        scn[tid] += t;
        __syncthreads();
    }
    scn[tid] -= c;          // exclusive local offset
    __syncthreads();
    cnt[tid] = 0;           // reuse as rank counters
    __syncthreads();
#pragma unroll
    for (int t = 0; t < 16; ++t) {
        if (dst[t] >= 0) {
            int b = dst[t] >> 9;
            int r = atomicAdd(&cnt[b], 1);
            int s = scn[b] + r;
            ebufL[s] = (((unsigned)(dst[t] & 511)) << 17) | (unsigned)src[t];
            gposL[s] = base[b] + r;
        }
    }
    __syncthreads();
    for (int s = tid; s < nv; s += 256) ebuf[gposL[s]] = ebufL[s];
}

// ---------------- stage 2: per-bucket CSR finalize (single-writer region -> L2 merge) ----------------

__global__ __launch_bounds__(256) void k_bucket(const unsigned* __restrict__ ebuf, const int* __restrict__ off,
                                                int* __restrict__ srcs, int N) {
    __shared__ int curL[512];
    int b = blockIdx.x;
    int n0 = b << 9;
    int n1 = min(n0 + 512, N);
    int nn = n1 - n0;
    int tid = threadIdx.x;
    for (int i = tid; i < nn; i += 256) curL[i] = off[n0 + i];
    __syncthreads();
    int e0 = off[n0], e1 = off[n1];
    for (int i = e0 + tid; i < e1; i += 256) {
        unsigned p = ebuf[i];
        int dl = (int)(p >> 17);
        int pos = atomicAdd(&curL[dl], 1);
        srcs[pos] = (int)(p & 0x1FFFFu);
    }
}

// ---------------- weight pre-pack (all 6 matrices, one launch) ----------------

struct W6 { const float* w[6]; };

__global__ __launch_bounds__(256) void k_packw6(W6 ws6, ushort* __restrict__ pk) {
    int m = blockIdx.x >> 6;
    int p = (blockIdx.x & 63) * 256 + threadIdx.x;   // 0..16383
    const float* W = ws6.w[m];
    ushort* o = pk + (size_t)m * 32768;
    int j = p & 7, l = (p >> 3) & 63, n = (p >> 9) & 7, kc = p >> 12;
    int row = kc * 32 + ((l >> 4) & 3) * 8 + j;
    int col = n * 16 + (l & 15);
    float wv = W[row * 128 + col];
    ushort hi = f2bf(wv);
    ushort lo = f2bf(wv - bf2f(hi));
    o[p] = hi;
    o[16384 + p] = lo;
}

// ---------------- aggregation (+ lazy BN/ReLU of input) ----------------

template <bool HASBN>
__global__ __launch_bounds__(256) void k_agg_bn(const float* __restrict__ X, float* __restrict__ T,
        const int* __restrict__ off, const int* __restrict__ srcs,
        const float* __restrict__ stats, const float* __restrict__ gamma, const float* __restrict__ beta,
        int N) {
    int gid = blockIdx.x * 256 + threadIdx.x;
    int w = gid >> 6;
    int lane = threadIdx.x & 63;
    int half = lane >> 5;
    int c4 = lane & 31;
    int node = w * 2 + half;
    if (node >= N) return;

    float4 gA = make_float4(1.f, 1.f, 1.f, 1.f), bA = make_float4(0.f, 0.f, 0.f, 0.f);
    if (HASBN) {
        int c = c4 * 4;
        float invN = 1.0f / (float)N;
#pragma unroll
        for (int t = 0; t < 4; ++t) {
            float m = stats[c + t] * invN;
            float v = stats[128 + c + t] * invN - m * m;
            float r = rsqrtf(v + BN_EPS);
            float g = gamma[c + t] * r;
            float b = beta[c + t] - m * g;
            ((float*)&gA)[t] = g;
            ((float*)&bA)[t] = b;
        }
    }

    const float4* X4 = (const float4*)X;
    auto ldf = [&](int u) -> float4 {
        float4 v = X4[(size_t)u * 32 + c4];
        if (HASBN) {
            v.x = fmaxf(fmaf(v.x, gA.x, bA.x), 0.f);
            v.y = fmaxf(fmaf(v.y, gA.y, bA.y), 0.f);
            v.z = fmaxf(fmaf(v.z, gA.z, bA.z), 0.f);
            v.w = fmaxf(fmaf(v.w, gA.w, bA.w), 0.f);
        }
        return v;
    };

    float4 acc = ldf(node);
    int s = off[node], e = off[node + 1];
    int j = s;
    for (; j + 7 < e; j += 8) {
        int u0 = srcs[j], u1 = srcs[j + 1], u2 = srcs[j + 2], u3 = srcs[j + 3];
        int u4 = srcs[j + 4], u5 = srcs[j + 5], u6 = srcs[j + 6], u7 = srcs[j + 7];
        float4 a = ldf(u0), b = ldf(u1), c = ldf(u2), d = ldf(u3);
        float4 p = ldf(u4), q = ldf(u5), r = ldf(u6), t = ldf(u7);
        acc.x += ((a.x + b.x) + (c.x + d.x)) + ((p.x + q.x) + (r.x + t.x));
        acc.y += ((a.y + b.y) + (c.y + d.y)) + ((p.y + q.y) + (r.y + t.y));
        acc.z += ((a.z + b.z) + (c.z + d.z)) + ((p.z + q.z) + (r.z + t.z));
        acc.w += ((a.w + b.w) + (c.w + d.w)) + ((p.w + q.w) + (r.w + t.w));
    }
    for (; j + 1 < e; j += 2) {
        float4 a = ldf(srcs[j]), b = ldf(srcs[j + 1]);
        acc.x += a.x + b.x; acc.y += a.y + b.y; acc.z += a.z + b.z; acc.w += a.w + b.w;
    }
    for (; j < e; ++j) {
        float4 a = ldf(srcs[j]);
        acc.x += a.x; acc.y += a.y; acc.z += a.z; acc.w += a.w;
    }
    ((float4*)T)[(size_t)node * 32 + c4] = acc;
}

// ---------------- fused MLP pair: GEMM1 + ReLU -> LDS restage -> GEMM2 + stats ----------------
// per-wave 32-row tile; LDS swizzled at 16B granule: c4' = c4 ^ (row & 7)

__global__ __launch_bounds__(256, 2) void k_mlp_pair(const float* __restrict__ A, float* __restrict__ out,
        const ushort* __restrict__ pk1, const float* __restrict__ b1,
        const ushort* __restrict__ pk2, const float* __restrict__ b2,
        float* __restrict__ stats, int N) {
    __shared__ float tile[4 * 32 * 128];   // 64 KB
    int tid = threadIdx.x;
    int wid = tid >> 6, l = tid & 63;
    int lr = l & 15, lg = l >> 4;
    int r0 = blockIdx.x * 128 + wid * 32;
    int wbase = wid * 32 * 128;

    const f32x4* A4 = (const f32x4*)A;
    const s16x8* B1 = (const s16x8*)pk1;
    const s16x8* B2 = (const s16x8*)pk2;

    f32x4 acc[2][8];
#pragma unroll
    for (int m = 0; m < 2; ++m)
#pragma unroll
        for (int n = 0; n < 8; ++n) acc[m][n] = (f32x4){0.f, 0.f, 0.f, 0.f};

    // ---- GEMM1 (A from global) ----
#pragma unroll
    for (int kc = 0; kc < 4; ++kc) {
        s16x8 ahi[2], alo[2];
#pragma unroll
        for (int m = 0; m < 2; ++m) {
            int row = min(r0 + m * 16 + lr, N - 1);
            f32x4 v0 = A4[(size_t)row * 32 + kc * 8 + lg * 2];
            f32x4 v1 = A4[(size_t)row * 32 + kc * 8 + lg * 2 + 1];
            float f[8] = {v0.x, v0.y, v0.z, v0.w, v1.x, v1.y, v1.z, v1.w};
#pragma unroll
            for (int j = 0; j < 8; ++j) {
                ushort hi = f2bf(f[j]);
                ahi[m][j] = (short)hi;
                alo[m][j] = (short)f2bf(f[j] - bf2f(hi));
            }
        }
#pragma unroll
        for (int n = 0; n < 8; ++n) {
            int fi = (kc * 8 + n) * 64 + l;
            s16x8 bhi = B1[fi];
            s16x8 blo = B1[2048 + fi];
#pragma unroll
            for (int m = 0; m < 2; ++m) {
                acc[m][n] = __builtin_amdgcn_mfma_f32_16x16x32_bf16(ahi[m], bhi, acc[m][n], 0, 0, 0);
                acc[m][n] = __builtin_amdgcn_mfma_f32_16x16x32_bf16(alo[m], bhi, acc[m][n], 0, 0, 0);
                acc[m][n] = __builtin_amdgcn_mfma_f32_16x16x32_bf16(ahi[m], blo, acc[m][n], 0, 0, 0);
            }
        }
    }

    // ---- epilogue1: bias + ReLU, restage to LDS (swizzled) ----
#pragma unroll
    for (int n = 0; n < 8; ++n) {
        float bv = b1[n * 16 + lr];
        int c4 = n * 4 + (lr >> 2);
        int e = lr & 3;
#pragma unroll
        for (int m = 0; m < 2; ++m) {
#pragma unroll
            for (int i = 0; i < 4; ++i) {
                int row = m * 16 + lg * 4 + i;
                float v = fmaxf(acc[m][n][i] + bv, 0.f);
                tile[wbase + row * 128 + ((c4 ^ (row & 7)) << 2) + e] = v;
            }
        }
    }
    __syncthreads();

    // ---- GEMM2 (A from LDS) ----
#pragma unroll
    for (int m = 0; m < 2; ++m)
#pragma unroll
        for (int n = 0; n < 8; ++n) acc[m][n] = (f32x4){0.f, 0.f, 0.f, 0.f};

#pragma unroll
    for (int kc = 0; kc < 4; ++kc) {
        s16x8 ahi[2], alo[2];
#pragma unroll
        for (int m = 0; m < 2; ++m) {
            int row = m * 16 + lr;
            float f[8];
#pragma unroll
            for (int h = 0; h < 2; ++h) {
                int k4 = kc * 8 + lg * 2 + h;
                f32x4 v = *(const f32x4*)&tile[wbase + row * 128 + ((k4 ^ (row & 7)) << 2)];
                f[h * 4 + 0] = v.x; f[h * 4 + 1] = v.y; f[h * 4 + 2] = v.z; f[h * 4 + 3] = v.w;
            }
#pragma unroll
            for (int j = 0; j < 8; ++j) {
                ushort hi = f2bf(f[j]);
                ahi[m][j] = (short)hi;
                alo[m][j] = (short)f2bf(f[j] - bf2f(hi));
            }
        }
#pragma unroll
        for (int n = 0; n < 8; ++n) {
            int fi = (kc * 8 + n) * 64 + l;
            s16x8 bhi = B2[fi];
            s16x8 blo = B2[2048 + fi];
#pragma unroll
            for (int m = 0; m < 2; ++m) {
                acc[m][n] = __builtin_amdgcn_mfma_f32_16x16x32_bf16(ahi[m], bhi, acc[m][n], 0, 0, 0);
                acc[m][n] = __builtin_amdgcn_mfma_f32_16x16x32_bf16(alo[m], bhi, acc[m][n], 0, 0, 0);
                acc[m][n] = __builtin_amdgcn_mfma_f32_16x16x32_bf16(ahi[m], blo, acc[m][n], 0, 0, 0);
            }
        }
    }
    __syncthreads();   // LDS reads done before stats overlay

    // ---- epilogue2: bias, stats, store ----
    float s1[8], s2[8];
#pragma unroll
    for (int n = 0; n < 8; ++n) { s1[n] = 0.f; s2[n] = 0.f; }

#pragma unroll
    for (int n = 0; n < 8; ++n) {
        float bv = b2[n * 16 + lr];
#pragma unroll
        for (int m = 0; m < 2; ++m) {
#pragma unroll
            for (int i = 0; i < 4; ++i) {
                int r = r0 + m * 16 + lg * 4 + i;
                if (r < N) {
                    float v = acc[m][n][i] + bv;
                    s1[n] += v;
                    s2[n] += v * v;
                    out[(size_t)r * 128 + n * 16 + lr] = v;
                }
            }
        }
    }

    float* ls = tile;   // overlay [4][256]
#pragma unroll
    for (int n = 0; n < 8; ++n) {
        float a = s1[n], b = s2[n];
        a += __shfl_xor(a, 16, 64); a += __shfl_xor(a, 32, 64);
        b += __shfl_xor(b, 16, 64); b += __shfl_xor(b, 32, 64);
        if (lg == 0) {
            ls[wid * 256 + n * 16 + lr] = a;
            ls[wid * 256 + 128 + n * 16 + lr] = b;
        }
    }
    __syncthreads();
    float t = ls[tid] + ls[256 + tid] + ls[512 + tid] + ls[768 + tid];
    atomicAdd(&stats[tid], t);
}

// ---------------- segmented mean-pool accumulate of f(h) (read-only) ----------------

__global__ __launch_bounds__(128) void k_pool(const float* __restrict__ h, const float* __restrict__ stats,
                                              const float* __restrict__ gamma, const float* __restrict__ beta,
                                              const int* __restrict__ batch, float* __restrict__ pool,
                                              int loff, int N) {
    int c = threadIdx.x;
    const float invN = 1.0f / (float)N;
    float mean = stats[c] * invN;
    float var = stats[128 + c] * invN - mean * mean;
    float rstd = rsqrtf(var + BN_EPS);
    float gsc = gamma[c] * rstd;
    float bs = beta[c] - mean * gsc;

    int r0 = blockIdx.x * 64;
    int r1 = min(r0 + 64, N);
    float acc = 0.f;
    int curg = -1;
    for (int r = r0; r < r1; ++r) {
        float v = h[(size_t)r * 128 + c];
        float hv = fmaxf(fmaf(v, gsc, bs), 0.f);
        int g = batch[r];
        if (g != curg) {
            if (curg >= 0) atomicAdd(&pool[(size_t)curg * 384 + loff + c], acc);
            curg = g;
            acc = hv;
        } else {
            acc += hv;
        }
    }
    if (curg >= 0) atomicAdd(&pool[(size_t)curg * 384 + loff + c], acc);
}

// ---------------- final linear + row L2-normalize ----------------

__global__ __launch_bounds__(128) void k_final(const float* __restrict__ pool, const int* __restrict__ gcnt,
                                               const float* __restrict__ Wl, const float* __restrict__ bl,
                                               float* __restrict__ out) {
    __shared__ float sh[384];
    __shared__ float red[128];
    int g = blockIdx.x;
    int tid = threadIdx.x;
    float inv = 1.0f / fmaxf((float)gcnt[g], 1.0f);
    for (int t = tid; t < 384; t += 128) sh[t] = pool[(size_t)g * 384 + t] * inv;
    __syncthreads();
    float acc = bl[tid];
    for (int k = 0; k < 384; ++k) acc = fmaf(sh[k], Wl[(size_t)k * 128 + tid], acc);
    red[tid] = acc * acc;
    __syncthreads();
    for (int s = 64; s > 0; s >>= 1) {
        if (tid < s) red[tid] += red[tid + s];
        __syncthreads();
    }
    float norm = sqrtf(red[0]);
    float scale = 1.0f / fmaxf(norm, 1e-12f);
    out[(size_t)g * 128 + tid] = acc * scale;
}

// ---------------- host ----------------

extern "C" void kernel_launch(void* const* d_in, const int* in_sizes, int n_in,
                              void* d_out, int out_size, void* d_ws, size_t ws_size,
                              hipStream_t stream) {
    const float* x = (const float*)d_in[0];
    const int* edge_index = (const int*)d_in[1];
    const int* batch = (const int*)d_in[2];
    const float* Wa[3] = {(const float*)d_in[3], (const float*)d_in[9], (const float*)d_in[15]};
    const float* ba[3] = {(const float*)d_in[4], (const float*)d_in[10], (const float*)d_in[16]};
    const float* Wb[3] = {(const float*)d_in[5], (const float*)d_in[11], (const float*)d_in[17]};
    const float* bb[3] = {(const float*)d_in[6], (const float*)d_in[12], (const float*)d_in[18]};
    const float* gm[3] = {(const float*)d_in[7], (const float*)d_in[13], (const float*)d_in[19]};
    const float* be[3] = {(const float*)d_in[8], (const float*)d_in[14], (const float*)d_in[20]};
    const float* Wl = (const float*)d_in[21];
    const float* bl = (const float*)d_in[22];
    float* out = (float*)d_out;

    const int N = N_NODES, E = N_EDGES, G = N_GRAPHS;
    const int* e_src = edge_index;
    const int* e_dst = edge_index + E;

    char* ws = (char*)d_ws;
    size_t o = 0;
    auto alloc = [&](size_t bytes) -> char* {
        char* p = ws + o;
        o = (o + bytes + 255) & ~(size_t)255;
        return p;
    };
    int* deg = (int*)alloc((size_t)N * 4);
    int* off = (int*)alloc((size_t)(N + 1) * 4);
    int* srcs = (int*)alloc((size_t)E * 4);
    int* gcnt = (int*)alloc((size_t)G * 4);
    int* partials = (int*)alloc(128 * 4);
    int* sbase = (int*)alloc(128 * 4);
    int* gcur = (int*)alloc(256 * 4);
    float* stats = (float*)alloc(3 * 256 * 4);
    ushort* wpk = (ushort*)alloc(6 * 32768 * 2);
    float* pool = (float*)alloc((size_t)G * 384 * 4);
    float* P = (float*)alloc((size_t)N * 128 * 4);
    float* Q = (float*)alloc((size_t)N * 128 * 4);
    unsigned* ebuf = (unsigned*)Q;   // ebuf dead before Q's first write (layer-1 agg)
    (void)ws_size;

    hipMemsetAsync(deg, 0, (size_t)N * 4, stream);
    hipMemsetAsync(gcnt, 0, (size_t)G * 4, stream);
    hipMemsetAsync(stats, 0, 3 * 256 * 4, stream);
    hipMemsetAsync(pool, 0, (size_t)G * 384 * 4, stream);

    const int E4 = E / 4, N4 = N / 4;
    const int HB = (E4 + 255) / 256;
    const int GB = (N4 + 255) / 256;
    const int SCB = (N + 1023) / 1024;

    k_hist_gcnt<<<HB + GB, 256, 0, stream>>>((const int4*)e_dst, deg, (const int4*)batch, gcnt, E4, N4, HB);
    k_scan1<<<SCB, 1024, 0, stream>>>(deg, off, partials, N);
    k_scan2<<<1, 64, 0, stream>>>(partials, sbase, off, SCB, N);
    k_scan3<<<SCB, 1024, 0, stream>>>(deg, off, sbase, N);
    k_binit<<<(NBKT + 63) / 64, 64, 0, stream>>>(off, gcur, N);
    k_part<<<(E + PART_CHUNK - 1) / PART_CHUNK, 256, 0, stream>>>(e_src, e_dst, gcur, ebuf, E);
    k_bucket<<<NBKT, 256, 0, stream>>>(ebuf, off, srcs, N);

    W6 w6;
    w6.w[0] = Wa[0]; w6.w[1] = Wb[0]; w6.w[2] = Wa[1];
    w6.w[3] = Wb[1]; w6.w[4] = Wa[2]; w6.w[5] = Wb[2];
    k_packw6<<<384, 256, 0, stream>>>(w6, wpk);

    const int aggBlocks = (N * 32 + 255) / 256;
    const int mlpBlocks = (N + 127) / 128;
    const int poolBlocks = (N + 63) / 64;

    float* bufIn[3] = {(float*)x, P, Q};
    float* bufOut[3] = {P, Q, P};
    for (int l = 0; l < 3; ++l) {
        float* T = bufOut[l];
        float* statsl = stats + l * 256;
        if (l == 0)
            k_agg_bn<false><<<aggBlocks, 256, 0, stream>>>(bufIn[l], T, off, srcs, nullptr, nullptr, nullptr, N);
        else
            k_agg_bn<true><<<aggBlocks, 256, 0, stream>>>(bufIn[l], T, off, srcs, stats + (l - 1) * 256,
                                                          gm[l - 1], be[l - 1], N);
        k_mlp_pair<<<mlpBlocks, 256, 0, stream>>>(T, T, wpk + (size_t)(2 * l) * 32768, ba[l],
                                                  wpk + (size_t)(2 * l + 1) * 32768, bb[l], statsl, N);
        k_pool<<<poolBlocks, 128, 0, stream>>>(T, statsl, gm[l], be[l], batch, pool, l * 128, N);
    }

    k_final<<<G, 128, 0, stream>>>(pool, gcnt, Wl, bl, out);
}

// Round 5
// 701.229 us; speedup vs baseline: 1.9442x; 1.1654x over previous
//
#include <hip/hip_runtime.h>
#include <hip/hip_bf16.h>

#define N_NODES 100000
#define N_EDGES 1600000
#define N_GRAPHS 512
#define BN_EPS 1e-5f
#define NBKT 196          // buckets of 512 nodes: dst>>9
#define PART_CHUNK 4096

typedef float f32x4 __attribute__((ext_vector_type(4)));
typedef short s16x8 __attribute__((ext_vector_type(8)));

__device__ inline ushort f2bf(float f) {
    union { float f; unsigned u; } v; v.f = f;
    unsigned u = v.u;
    unsigned r = (u + 0x7FFFu + ((u >> 16) & 1u)) >> 16;
    return (ushort)r;
}
__device__ inline float bf2f(ushort h) {
    union { unsigned u; float f; } v; v.u = ((unsigned)h) << 16;
    return v.f;
}

// ---------------- bucket-count histogram (196 coarse bins via LDS) ----------------

__global__ __launch_bounds__(256) void k_bcnt(const int4* __restrict__ dst4, int* __restrict__ bcnt, int E4) {
    __shared__ int h[NBKT];
    int tid = threadIdx.x;
    for (int i = tid; i < NBKT; i += 256) h[i] = 0;
    __syncthreads();
    for (int t = blockIdx.x * 256 + tid; t < E4; t += gridDim.x * 256) {
        int4 d = dst4[t];
        atomicAdd(&h[d.x >> 9], 1);
        atomicAdd(&h[d.y >> 9], 1);
        atomicAdd(&h[d.z >> 9], 1);
        atomicAdd(&h[d.w >> 9], 1);
    }
    __syncthreads();
    for (int i = tid; i < NBKT; i += 256) {
        int v = h[i];
        if (v) atomicAdd(&bcnt[i], v);
    }
}

// ---------------- bucket base scan (tiny) ----------------

__global__ __launch_bounds__(256) void k_bscan(const int* __restrict__ bcnt, int* __restrict__ bbase,
                                               int* __restrict__ gcur) {
    __shared__ int buf[256];
    int tid = threadIdx.x;
    int v = (tid < NBKT) ? bcnt[tid] : 0;
    buf[tid] = v;
    __syncthreads();
    for (int st = 1; st < 256; st <<= 1) {
        int t = (tid >= st) ? buf[tid - st] : 0;
        __syncthreads();
        buf[tid] += t;
        __syncthreads();
    }
    int excl = buf[tid] - v;
    if (tid < NBKT) {
        bbase[tid] = excl;
        gcur[tid] = excl;
    }
    if (tid == NBKT - 1) bbase[NBKT] = excl + v;
}

// ---------------- graph counts via binary search on sorted batch ----------------

__global__ __launch_bounds__(256) void k_gstart(const int* __restrict__ batch, int* __restrict__ gcnt, int N) {
    int g = blockIdx.x * 256 + threadIdx.x;
    if (g >= N_GRAPHS) return;
    auto lb = [&](int key) {
        int lo = 0, hi = N;
        while (lo < hi) {
            int mid = (lo + hi) >> 1;
            if (batch[mid] < key) lo = mid + 1; else hi = mid;
        }
        return lo;
    };
    gcnt[g] = lb(g + 1) - lb(g);
}

// ---------------- stage 1: partition edges into 196 coarse buckets ----------------
// writes packed records (dstLow9 << 17) | src  in bucket-grouped runs

__global__ __launch_bounds__(256) void k_part(const int* __restrict__ esrc, const int* __restrict__ edst,
                                              int* __restrict__ gcur, unsigned* __restrict__ ebuf, int E) {
    __shared__ int cnt[256], base[256], scn[256];
    __shared__ unsigned ebufL[PART_CHUNK];
    __shared__ int gposL[PART_CHUNK];
    int tid = threadIdx.x;
    int e0 = blockIdx.x * PART_CHUNK;
    int nv = min(PART_CHUNK, E - e0);
    int src[16], dst[16];
    cnt[tid] = 0;
    __syncthreads();
    const int4* s4 = (const int4*)(esrc + e0);
    const int4* d4 = (const int4*)(edst + e0);
    int n4 = nv >> 2;
#pragma unroll
    for (int t = 0; t < 4; ++t) {
        int i4 = t * 256 + tid;
        if (i4 < n4) {
            int4 s = s4[i4];
            int4 d = d4[i4];
            src[t * 4 + 0] = s.x; src[t * 4 + 1] = s.y; src[t * 4 + 2] = s.z; src[t * 4 + 3] = s.w;
            dst[t * 4 + 0] = d.x; dst[t * 4 + 1] = d.y; dst[t * 4 + 2] = d.z; dst[t * 4 + 3] = d.w;
            atomicAdd(&cnt[d.x >> 9], 1);
            atomicAdd(&cnt[d.y >> 9], 1);
            atomicAdd(&cnt[d.z >> 9], 1);
            atomicAdd(&cnt[d.w >> 9], 1);
        } else {
            dst[t * 4 + 0] = -1; dst[t * 4 + 1] = -1; dst[t * 4 + 2] = -1; dst[t * 4 + 3] = -1;
            src[t * 4 + 0] = 0; src[t * 4 + 1] = 0; src[t * 4 + 2] = 0; src[t * 4 + 3] = 0;
        }
    }
    __syncthreads();
    int c = cnt[tid];
    if (tid < NBKT) base[tid] = atomicAdd(&gcur[tid], c);
    scn[tid] = c;
    __syncthreads();
    for (int st = 1; st < 256; st <<= 1) {
        int t = (tid >= st) ? scn[tid - st] : 0;
        __syncthreads();
        scn[tid] += t;
        __syncthreads();
    }
    scn[tid] -= c;          // exclusive local offset
    __syncthreads();
    cnt[tid] = 0;           // reuse as rank counters
    __syncthreads();
#pragma unroll
    for (int t = 0; t < 16; ++t) {
        if (dst[t] >= 0) {
            int b = dst[t] >> 9;
            int r = atomicAdd(&cnt[b], 1);
            int s = scn[b] + r;
            ebufL[s] = (((unsigned)(dst[t] & 511)) << 17) | (unsigned)src[t];
            gposL[s] = base[b] + r;
        }
    }
    __syncthreads();
    for (int s = tid; s < nv; s += 256) ebuf[gposL[s]] = ebufL[s];
}

// ---------------- stage 2: per-bucket degree count + local scan -> off, then CSR scatter ----------------

__global__ __launch_bounds__(256) void k_bucket(const unsigned* __restrict__ ebuf, const int* __restrict__ bbase,
                                                int* __restrict__ off, int* __restrict__ srcs, int N) {
    __shared__ int degL[512];
    __shared__ int s2[256];
    int b = blockIdx.x;
    int n0 = b << 9;
    int nn = min(512, N - n0);
    int tid = threadIdx.x;
    for (int i = tid; i < nn; i += 256) degL[i] = 0;
    __syncthreads();
    int e0 = bbase[b], e1 = bbase[b + 1];
    for (int i = e0 + tid; i < e1; i += 256) atomicAdd(&degL[ebuf[i] >> 17], 1);
    __syncthreads();
    // local scan of nn degrees (2 per thread)
    int a0 = (2 * tid < nn) ? degL[2 * tid] : 0;
    int a1 = (2 * tid + 1 < nn) ? degL[2 * tid + 1] : 0;
    int ps = a0 + a1;
    s2[tid] = ps;
    __syncthreads();
    for (int st = 1; st < 256; st <<= 1) {
        int t = (tid >= st) ? s2[tid - st] : 0;
        __syncthreads();
        s2[tid] += t;
        __syncthreads();
    }
    int excl = s2[tid] - ps;
    // write off + init local cursors (degL reuse)
    if (2 * tid < nn) { off[n0 + 2 * tid] = e0 + excl; degL[2 * tid] = e0 + excl; }
    if (2 * tid + 1 < nn) { off[n0 + 2 * tid + 1] = e0 + excl + a0; degL[2 * tid + 1] = e0 + excl + a0; }
    if (b == NBKT - 1 && tid == 0) off[N] = e1;
    __syncthreads();
    for (int i = e0 + tid; i < e1; i += 256) {
        unsigned p = ebuf[i];
        int dl = (int)(p >> 17);
        int pos = atomicAdd(&degL[dl], 1);
        srcs[pos] = (int)(p & 0x1FFFFu);
    }
}

// ---------------- weight pre-pack (all 6 matrices, one launch) ----------------

struct W6 { const float* w[6]; };

__global__ __launch_bounds__(256) void k_packw6(W6 ws6, ushort* __restrict__ pk) {
    int m = blockIdx.x >> 6;
    int p = (blockIdx.x & 63) * 256 + threadIdx.x;   // 0..16383
    const float* W = ws6.w[m];
    ushort* o = pk + (size_t)m * 32768;
    int j = p & 7, l = (p >> 3) & 63, n = (p >> 9) & 7, kc = p >> 12;
    int row = kc * 32 + ((l >> 4) & 3) * 8 + j;
    int col = n * 16 + (l & 15);
    float wv = W[row * 128 + col];
    ushort hi = f2bf(wv);
    ushort lo = f2bf(wv - bf2f(hi));
    o[p] = hi;
    o[16384 + p] = lo;
}

// ---------------- aggregation (+ lazy BN/ReLU of input) ----------------

template <bool HASBN>
__global__ __launch_bounds__(256) void k_agg_bn(const float* __restrict__ X, float* __restrict__ T,
        const int* __restrict__ off, const int* __restrict__ srcs,
        const float* __restrict__ stats, const float* __restrict__ gamma, const float* __restrict__ beta,
        int N) {
    int gid = blockIdx.x * 256 + threadIdx.x;
    int w = gid >> 6;
    int lane = threadIdx.x & 63;
    int half = lane >> 5;
    int c4 = lane & 31;
    int node = w * 2 + half;
    if (node >= N) return;

    float4 gA = make_float4(1.f, 1.f, 1.f, 1.f), bA = make_float4(0.f, 0.f, 0.f, 0.f);
    if (HASBN) {
        int c = c4 * 4;
        float invN = 1.0f / (float)N;
#pragma unroll
        for (int t = 0; t < 4; ++t) {
            float m = stats[c + t] * invN;
            float v = stats[128 + c + t] * invN - m * m;
            float r = rsqrtf(v + BN_EPS);
            float g = gamma[c + t] * r;
            float b = beta[c + t] - m * g;
            ((float*)&gA)[t] = g;
            ((float*)&bA)[t] = b;
        }
    }

    const float4* X4 = (const float4*)X;
    auto ldf = [&](int u) -> float4 {
        float4 v = X4[(size_t)u * 32 + c4];
        if (HASBN) {
            v.x = fmaxf(fmaf(v.x, gA.x, bA.x), 0.f);
            v.y = fmaxf(fmaf(v.y, gA.y, bA.y), 0.f);
            v.z = fmaxf(fmaf(v.z, gA.z, bA.z), 0.f);
            v.w = fmaxf(fmaf(v.w, gA.w, bA.w), 0.f);
        }
        return v;
    };

    float4 acc = ldf(node);
    int s = off[node], e = off[node + 1];
    int j = s;
    for (; j + 7 < e; j += 8) {
        int u0 = srcs[j], u1 = srcs[j + 1], u2 = srcs[j + 2], u3 = srcs[j + 3];
        int u4 = srcs[j + 4], u5 = srcs[j + 5], u6 = srcs[j + 6], u7 = srcs[j + 7];
        float4 a = ldf(u0), b = ldf(u1), c = ldf(u2), d = ldf(u3);
        float4 p = ldf(u4), q = ldf(u5), r = ldf(u6), t = ldf(u7);
        acc.x += ((a.x + b.x) + (c.x + d.x)) + ((p.x + q.x) + (r.x + t.x));
        acc.y += ((a.y + b.y) + (c.y + d.y)) + ((p.y + q.y) + (r.y + t.y));
        acc.z += ((a.z + b.z) + (c.z + d.z)) + ((p.z + q.z) + (r.z + t.z));
        acc.w += ((a.w + b.w) + (c.w + d.w)) + ((p.w + q.w) + (r.w + t.w));
    }
    for (; j + 1 < e; j += 2) {
        float4 a = ldf(srcs[j]), b = ldf(srcs[j + 1]);
        acc.x += a.x + b.x; acc.y += a.y + b.y; acc.z += a.z + b.z; acc.w += a.w + b.w;
    }
    for (; j < e; ++j) {
        float4 a = ldf(srcs[j]);
        acc.x += a.x; acc.y += a.y; acc.z += a.z; acc.w += a.w;
    }
    ((float4*)T)[(size_t)node * 32 + c4] = acc;
}

// ---------------- fused MLP pair: GEMM1 + ReLU -> LDS restage -> GEMM2 + stats ----------------
// per-wave 32-row tile; LDS swizzled at 16B granule: c4' = c4 ^ (row & 7)

__global__ __launch_bounds__(256, 2) void k_mlp_pair(const float* __restrict__ A, float* __restrict__ out,
        const ushort* __restrict__ pk1, const float* __restrict__ b1,
        const ushort* __restrict__ pk2, const float* __restrict__ b2,
        float* __restrict__ stats, int N) {
    __shared__ float tile[4 * 32 * 128];   // 64 KB
    int tid = threadIdx.x;
    int wid = tid >> 6, l = tid & 63;
    int lr = l & 15, lg = l >> 4;
    int r0 = blockIdx.x * 128 + wid * 32;
    int wbase = wid * 32 * 128;

    const f32x4* A4 = (const f32x4*)A;
    const s16x8* B1 = (const s16x8*)pk1;
    const s16x8* B2 = (const s16x8*)pk2;

    f32x4 acc[2][8];
#pragma unroll
    for (int m = 0; m < 2; ++m)
#pragma unroll
        for (int n = 0; n < 8; ++n) acc[m][n] = (f32x4){0.f, 0.f, 0.f, 0.f};

    // ---- GEMM1 (A from global) ----
#pragma unroll
    for (int kc = 0; kc < 4; ++kc) {
        s16x8 ahi[2], alo[2];
#pragma unroll
        for (int m = 0; m < 2; ++m) {
            int row = min(r0 + m * 16 + lr, N - 1);
            f32x4 v0 = A4[(size_t)row * 32 + kc * 8 + lg * 2];
            f32x4 v1 = A4[(size_t)row * 32 + kc * 8 + lg * 2 + 1];
            float f[8] = {v0.x, v0.y, v0.z, v0.w, v1.x, v1.y, v1.z, v1.w};
#pragma unroll
            for (int j = 0; j < 8; ++j) {
                ushort hi = f2bf(f[j]);
                ahi[m][j] = (short)hi;
                alo[m][j] = (short)f2bf(f[j] - bf2f(hi));
            }
        }
#pragma unroll
        for (int n = 0; n < 8; ++n) {
            int fi = (kc * 8 + n) * 64 + l;
            s16x8 bhi = B1[fi];
            s16x8 blo = B1[2048 + fi];
#pragma unroll
            for (int m = 0; m < 2; ++m) {
                acc[m][n] = __builtin_amdgcn_mfma_f32_16x16x32_bf16(ahi[m], bhi, acc[m][n], 0, 0, 0);
                acc[m][n] = __builtin_amdgcn_mfma_f32_16x16x32_bf16(alo[m], bhi, acc[m][n], 0, 0, 0);
                acc[m][n] = __builtin_amdgcn_mfma_f32_16x16x32_bf16(ahi[m], blo, acc[m][n], 0, 0, 0);
            }
        }
    }

    // ---- epilogue1: bias + ReLU, restage to LDS (swizzled) ----
#pragma unroll
    for (int n = 0; n < 8; ++n) {
        float bv = b1[n * 16 + lr];
        int c4 = n * 4 + (lr >> 2);
        int e = lr & 3;
#pragma unroll
        for (int m = 0; m < 2; ++m) {
#pragma unroll
            for (int i = 0; i < 4; ++i) {
                int row = m * 16 + lg * 4 + i;
                float v = fmaxf(acc[m][n][i] + bv, 0.f);
                tile[wbase + row * 128 + ((c4 ^ (row & 7)) << 2) + e] = v;
            }
        }
    }
    __syncthreads();

    // ---- GEMM2 (A from LDS) ----
#pragma unroll
    for (int m = 0; m < 2; ++m)
#pragma unroll
        for (int n = 0; n < 8; ++n) acc[m][n] = (f32x4){0.f, 0.f, 0.f, 0.f};

#pragma unroll
    for (int kc = 0; kc < 4; ++kc) {
        s16x8 ahi[2], alo[2];
#pragma unroll
        for (int m = 0; m < 2; ++m) {
            int row = m * 16 + lr;
            float f[8];
#pragma unroll
            for (int h = 0; h < 2; ++h) {
                int k4 = kc * 8 + lg * 2 + h;
                f32x4 v = *(const f32x4*)&tile[wbase + row * 128 + ((k4 ^ (row & 7)) << 2)];
                f[h * 4 + 0] = v.x; f[h * 4 + 1] = v.y; f[h * 4 + 2] = v.z; f[h * 4 + 3] = v.w;
            }
#pragma unroll
            for (int j = 0; j < 8; ++j) {
                ushort hi = f2bf(f[j]);
                ahi[m][j] = (short)hi;
                alo[m][j] = (short)f2bf(f[j] - bf2f(hi));
            }
        }
#pragma unroll
        for (int n = 0; n < 8; ++n) {
            int fi = (kc * 8 + n) * 64 + l;
            s16x8 bhi = B2[fi];
            s16x8 blo = B2[2048 + fi];
#pragma unroll
            for (int m = 0; m < 2; ++m) {
                acc[m][n] = __builtin_amdgcn_mfma_f32_16x16x32_bf16(ahi[m], bhi, acc[m][n], 0, 0, 0);
                acc[m][n] = __builtin_amdgcn_mfma_f32_16x16x32_bf16(alo[m], bhi, acc[m][n], 0, 0, 0);
                acc[m][n] = __builtin_amdgcn_mfma_f32_16x16x32_bf16(ahi[m], blo, acc[m][n], 0, 0, 0);
            }
        }
    }
    __syncthreads();   // LDS reads done before stats overlay

    // ---- epilogue2: bias, stats, store ----
    float s1[8], s2[8];
#pragma unroll
    for (int n = 0; n < 8; ++n) { s1[n] = 0.f; s2[n] = 0.f; }

#pragma unroll
    for (int n = 0; n < 8; ++n) {
        float bv = b2[n * 16 + lr];
#pragma unroll
        for (int m = 0; m < 2; ++m) {
#pragma unroll
            for (int i = 0; i < 4; ++i) {
                int r = r0 + m * 16 + lg * 4 + i;
                if (r < N) {
                    float v = acc[m][n][i] + bv;
                    s1[n] += v;
                    s2[n] += v * v;
                    out[(size_t)r * 128 + n * 16 + lr] = v;
                }
            }
        }
    }

    float* ls = tile;   // overlay [4][256]
#pragma unroll
    for (int n = 0; n < 8; ++n) {
        float a = s1[n], b = s2[n];
        a += __shfl_xor(a, 16, 64); a += __shfl_xor(a, 32, 64);
        b += __shfl_xor(b, 16, 64); b += __shfl_xor(b, 32, 64);
        if (lg == 0) {
            ls[wid * 256 + n * 16 + lr] = a;
            ls[wid * 256 + 128 + n * 16 + lr] = b;
        }
    }
    __syncthreads();
    float t = ls[tid] + ls[256 + tid] + ls[512 + tid] + ls[768 + tid];
    atomicAdd(&stats[tid], t);
}

// ---------------- segmented mean-pool accumulate of f(h) (read-only) ----------------

__global__ __launch_bounds__(128) void k_pool(const float* __restrict__ h, const float* __restrict__ stats,
                                              const float* __restrict__ gamma, const float* __restrict__ beta,
                                              const int* __restrict__ batch, float* __restrict__ pool,
                                              int loff, int N) {
    int c = threadIdx.x;
    const float invN = 1.0f / (float)N;
    float mean = stats[c] * invN;
    float var = stats[128 + c] * invN - mean * mean;
    float rstd = rsqrtf(var + BN_EPS);
    float gsc = gamma[c] * rstd;
    float bs = beta[c] - mean * gsc;

    int r0 = blockIdx.x * 64;
    int r1 = min(r0 + 64, N);
    float acc = 0.f;
    int curg = -1;
    for (int r = r0; r < r1; ++r) {
        float v = h[(size_t)r * 128 + c];
        float hv = fmaxf(fmaf(v, gsc, bs), 0.f);
        int g = batch[r];
        if (g != curg) {
            if (curg >= 0) atomicAdd(&pool[(size_t)curg * 384 + loff + c], acc);
            curg = g;
            acc = hv;
        } else {
            acc += hv;
        }
    }
    if (curg >= 0) atomicAdd(&pool[(size_t)curg * 384 + loff + c], acc);
}

// ---------------- final linear + row L2-normalize ----------------

__global__ __launch_bounds__(128) void k_final(const float* __restrict__ pool, const int* __restrict__ gcnt,
                                               const float* __restrict__ Wl, const float* __restrict__ bl,
                                               float* __restrict__ out) {
    __shared__ float sh[384];
    __shared__ float red[128];
    int g = blockIdx.x;
    int tid = threadIdx.x;
    float inv = 1.0f / fmaxf((float)gcnt[g], 1.0f);
    for (int t = tid; t < 384; t += 128) sh[t] = pool[(size_t)g * 384 + t] * inv;
    __syncthreads();
    float acc = bl[tid];
    for (int k = 0; k < 384; ++k) acc = fmaf(sh[k], Wl[(size_t)k * 128 + tid], acc);
    red[tid] = acc * acc;
    __syncthreads();
    for (int s = 64; s > 0; s >>= 1) {
        if (tid < s) red[tid] += red[tid + s];
        __syncthreads();
    }
    float norm = sqrtf(red[0]);
    float scale = 1.0f / fmaxf(norm, 1e-12f);
    out[(size_t)g * 128 + tid] = acc * scale;
}

// ---------------- host ----------------

extern "C" void kernel_launch(void* const* d_in, const int* in_sizes, int n_in,
                              void* d_out, int out_size, void* d_ws, size_t ws_size,
                              hipStream_t stream) {
    const float* x = (const float*)d_in[0];
    const int* edge_index = (const int*)d_in[1];
    const int* batch = (const int*)d_in[2];
    const float* Wa[3] = {(const float*)d_in[3], (const float*)d_in[9], (const float*)d_in[15]};
    const float* ba[3] = {(const float*)d_in[4], (const float*)d_in[10], (const float*)d_in[16]};
    const float* Wb[3] = {(const float*)d_in[5], (const float*)d_in[11], (const float*)d_in[17]};
    const float* bb[3] = {(const float*)d_in[6], (const float*)d_in[12], (const float*)d_in[18]};
    const float* gm[3] = {(const float*)d_in[7], (const float*)d_in[13], (const float*)d_in[19]};
    const float* be[3] = {(const float*)d_in[8], (const float*)d_in[14], (const float*)d_in[20]};
    const float* Wl = (const float*)d_in[21];
    const float* bl = (const float*)d_in[22];
    float* out = (float*)d_out;

    const int N = N_NODES, E = N_EDGES, G = N_GRAPHS;
    const int* e_src = edge_index;
    const int* e_dst = edge_index + E;

    char* ws = (char*)d_ws;
    size_t o = 0;
    auto alloc = [&](size_t bytes) -> char* {
        char* p = ws + o;
        o = (o + bytes + 255) & ~(size_t)255;
        return p;
    };
    int* off = (int*)alloc((size_t)(N + 1) * 4);
    int* srcs = (int*)alloc((size_t)E * 4);
    int* gcnt = (int*)alloc((size_t)G * 4);
    int* bcnt = (int*)alloc(256 * 4);
    int* bbase = (int*)alloc(256 * 4);
    int* gcur = (int*)alloc(256 * 4);
    float* stats = (float*)alloc(3 * 256 * 4);
    ushort* wpk = (ushort*)alloc(6 * 32768 * 2);
    float* pool = (float*)alloc((size_t)G * 384 * 4);
    float* P = (float*)alloc((size_t)N * 128 * 4);
    float* Q = (float*)alloc((size_t)N * 128 * 4);
    unsigned* ebuf = (unsigned*)Q;   // ebuf dead before Q's first write (layer-2 agg)
    (void)ws_size;

    hipMemsetAsync(bcnt, 0, 256 * 4, stream);
    hipMemsetAsync(stats, 0, 3 * 256 * 4, stream);
    hipMemsetAsync(pool, 0, (size_t)G * 384 * 4, stream);

    const int E4 = E / 4;

    k_bcnt<<<256, 256, 0, stream>>>((const int4*)e_dst, bcnt, E4);
    k_bscan<<<1, 256, 0, stream>>>(bcnt, bbase, gcur);
    k_gstart<<<2, 256, 0, stream>>>(batch, gcnt, N);
    k_part<<<(E + PART_CHUNK - 1) / PART_CHUNK, 256, 0, stream>>>(e_src, e_dst, gcur, ebuf, E);
    k_bucket<<<NBKT, 256, 0, stream>>>(ebuf, bbase, off, srcs, N);

    W6 w6;
    w6.w[0] = Wa[0]; w6.w[1] = Wb[0]; w6.w[2] = Wa[1];
    w6.w[3] = Wb[1]; w6.w[4] = Wa[2]; w6.w[5] = Wb[2];
    k_packw6<<<384, 256, 0, stream>>>(w6, wpk);

    const int aggBlocks = (N * 32 + 255) / 256;
    const int mlpBlocks = (N + 127) / 128;
    const int poolBlocks = (N + 63) / 64;

    float* bufIn[3] = {(float*)x, P, Q};
    float* bufOut[3] = {P, Q, P};
    for (int l = 0; l < 3; ++l) {
        float* T = bufOut[l];
        float* statsl = stats + l * 256;
        if (l == 0)
            k_agg_bn<false><<<aggBlocks, 256, 0, stream>>>(bufIn[l], T, off, srcs, nullptr, nullptr, nullptr, N);
        else
            k_agg_bn<true><<<aggBlocks, 256, 0, stream>>>(bufIn[l], T, off, srcs, stats + (l - 1) * 256,
                                                          gm[l - 1], be[l - 1], N);
        k_mlp_pair<<<mlpBlocks, 256, 0, stream>>>(T, T, wpk + (size_t)(2 * l) * 32768, ba[l],
                                                  wpk + (size_t)(2 * l + 1) * 32768, bb[l], statsl, N);
        k_pool<<<poolBlocks, 128, 0, stream>>>(T, statsl, gm[l], be[l], batch, pool, l * 128, N);
    }

    k_final<<<G, 128, 0, stream>>>(pool, gcnt, Wl, bl, out);
}

// Round 6
// 557.454 us; speedup vs baseline: 2.4456x; 1.2579x over previous
//
#include <hip/hip_runtime.h>
#include <hip/hip_bf16.h>
#include <hip/hip_fp16.h>

#define N_NODES 100000
#define N_EDGES 1600000
#define N_GRAPHS 512
#define BN_EPS 1e-5f
#define NBKT 196          // buckets of 512 nodes: dst>>9
#define PART_CHUNK 4096

typedef float f32x4 __attribute__((ext_vector_type(4)));
typedef short s16x8 __attribute__((ext_vector_type(8)));

__device__ inline ushort f2bf(float f) {
    union { float f; unsigned u; } v; v.f = f;
    unsigned u = v.u;
    unsigned r = (u + 0x7FFFu + ((u >> 16) & 1u)) >> 16;
    return (ushort)r;
}
__device__ inline float bf2f(ushort h) {
    union { unsigned u; float f; } v; v.u = ((unsigned)h) << 16;
    return v.f;
}

// ---------------- bucket-count histogram (196 coarse bins via LDS) ----------------

__global__ __launch_bounds__(256) void k_bcnt(const int4* __restrict__ dst4, int* __restrict__ bcnt, int E4) {
    __shared__ int h[NBKT];
    int tid = threadIdx.x;
    for (int i = tid; i < NBKT; i += 256) h[i] = 0;
    __syncthreads();
    for (int t = blockIdx.x * 256 + tid; t < E4; t += gridDim.x * 256) {
        int4 d = dst4[t];
        atomicAdd(&h[d.x >> 9], 1);
        atomicAdd(&h[d.y >> 9], 1);
        atomicAdd(&h[d.z >> 9], 1);
        atomicAdd(&h[d.w >> 9], 1);
    }
    __syncthreads();
    for (int i = tid; i < NBKT; i += 256) {
        int v = h[i];
        if (v) atomicAdd(&bcnt[i], v);
    }
}

// ---------------- bucket base scan (tiny) ----------------

__global__ __launch_bounds__(256) void k_bscan(const int* __restrict__ bcnt, int* __restrict__ bbase,
                                               int* __restrict__ gcur) {
    __shared__ int buf[256];
    int tid = threadIdx.x;
    int v = (tid < NBKT) ? bcnt[tid] : 0;
    buf[tid] = v;
    __syncthreads();
    for (int st = 1; st < 256; st <<= 1) {
        int t = (tid >= st) ? buf[tid - st] : 0;
        __syncthreads();
        buf[tid] += t;
        __syncthreads();
    }
    int excl = buf[tid] - v;
    if (tid < NBKT) {
        bbase[tid] = excl;
        gcur[tid] = excl;
    }
    if (tid == NBKT - 1) bbase[NBKT] = excl + v;
}

// ---------------- graph counts via binary search on sorted batch ----------------

__global__ __launch_bounds__(256) void k_gstart(const int* __restrict__ batch, int* __restrict__ gcnt, int N) {
    int g = blockIdx.x * 256 + threadIdx.x;
    if (g >= N_GRAPHS) return;
    auto lb = [&](int key) {
        int lo = 0, hi = N;
        while (lo < hi) {
            int mid = (lo + hi) >> 1;
            if (batch[mid] < key) lo = mid + 1; else hi = mid;
        }
        return lo;
    };
    gcnt[g] = lb(g + 1) - lb(g);
}

// ---------------- x (fp32) -> fp16 copy ----------------

__global__ __launch_bounds__(256) void k_x2h(const float4* __restrict__ x4, uint4* __restrict__ xh, int n8) {
    int i = blockIdx.x * 256 + threadIdx.x;
    if (i >= n8) return;
    float4 a = x4[2 * i], b = x4[2 * i + 1];
    union { uint4 u4; __half h[8]; } cv;
    cv.h[0] = __float2half(a.x); cv.h[1] = __float2half(a.y);
    cv.h[2] = __float2half(a.z); cv.h[3] = __float2half(a.w);
    cv.h[4] = __float2half(b.x); cv.h[5] = __float2half(b.y);
    cv.h[6] = __float2half(b.z); cv.h[7] = __float2half(b.w);
    xh[i] = cv.u4;
}

// ---------------- stage 1: partition edges into 196 coarse buckets ----------------

__global__ __launch_bounds__(256) void k_part(const int* __restrict__ esrc, const int* __restrict__ edst,
                                              int* __restrict__ gcur, unsigned* __restrict__ ebuf, int E) {
    __shared__ int cnt[256], base[256], scn[256];
    __shared__ unsigned ebufL[PART_CHUNK];
    __shared__ int gposL[PART_CHUNK];
    int tid = threadIdx.x;
    int e0 = blockIdx.x * PART_CHUNK;
    int nv = min(PART_CHUNK, E - e0);
    int src[16], dst[16];
    cnt[tid] = 0;
    __syncthreads();
    const int4* s4 = (const int4*)(esrc + e0);
    const int4* d4 = (const int4*)(edst + e0);
    int n4 = nv >> 2;
#pragma unroll
    for (int t = 0; t < 4; ++t) {
        int i4 = t * 256 + tid;
        if (i4 < n4) {
            int4 s = s4[i4];
            int4 d = d4[i4];
            src[t * 4 + 0] = s.x; src[t * 4 + 1] = s.y; src[t * 4 + 2] = s.z; src[t * 4 + 3] = s.w;
            dst[t * 4 + 0] = d.x; dst[t * 4 + 1] = d.y; dst[t * 4 + 2] = d.z; dst[t * 4 + 3] = d.w;
            atomicAdd(&cnt[d.x >> 9], 1);
            atomicAdd(&cnt[d.y >> 9], 1);
            atomicAdd(&cnt[d.z >> 9], 1);
            atomicAdd(&cnt[d.w >> 9], 1);
        } else {
            dst[t * 4 + 0] = -1; dst[t * 4 + 1] = -1; dst[t * 4 + 2] = -1; dst[t * 4 + 3] = -1;
            src[t * 4 + 0] = 0; src[t * 4 + 1] = 0; src[t * 4 + 2] = 0; src[t * 4 + 3] = 0;
        }
    }
    __syncthreads();
    int c = cnt[tid];
    if (tid < NBKT) base[tid] = atomicAdd(&gcur[tid], c);
    scn[tid] = c;
    __syncthreads();
    for (int st = 1; st < 256; st <<= 1) {
        int t = (tid >= st) ? scn[tid - st] : 0;
        __syncthreads();
        scn[tid] += t;
        __syncthreads();
    }
    scn[tid] -= c;
    __syncthreads();
    cnt[tid] = 0;
    __syncthreads();
#pragma unroll
    for (int t = 0; t < 16; ++t) {
        if (dst[t] >= 0) {
            int b = dst[t] >> 9;
            int r = atomicAdd(&cnt[b], 1);
            int s = scn[b] + r;
            ebufL[s] = (((unsigned)(dst[t] & 511)) << 17) | (unsigned)src[t];
            gposL[s] = base[b] + r;
        }
    }
    __syncthreads();
    for (int s = tid; s < nv; s += 256) ebuf[gposL[s]] = ebufL[s];
}

// ---------------- stage 2: per-bucket degree + local scan -> off, then CSR scatter ----------------

__global__ __launch_bounds__(256) void k_bucket(const unsigned* __restrict__ ebuf, const int* __restrict__ bbase,
                                                int* __restrict__ off, int* __restrict__ srcs, int N) {
    __shared__ int degL[512];
    __shared__ int s2[256];
    int b = blockIdx.x;
    int n0 = b << 9;
    int nn = min(512, N - n0);
    int tid = threadIdx.x;
    for (int i = tid; i < nn; i += 256) degL[i] = 0;
    __syncthreads();
    int e0 = bbase[b], e1 = bbase[b + 1];
    for (int i = e0 + tid; i < e1; i += 256) atomicAdd(&degL[ebuf[i] >> 17], 1);
    __syncthreads();
    int a0 = (2 * tid < nn) ? degL[2 * tid] : 0;
    int a1 = (2 * tid + 1 < nn) ? degL[2 * tid + 1] : 0;
    int ps = a0 + a1;
    s2[tid] = ps;
    __syncthreads();
    for (int st = 1; st < 256; st <<= 1) {
        int t = (tid >= st) ? s2[tid - st] : 0;
        __syncthreads();
        s2[tid] += t;
        __syncthreads();
    }
    int excl = s2[tid] - ps;
    if (2 * tid < nn) { off[n0 + 2 * tid] = e0 + excl; degL[2 * tid] = e0 + excl; }
    if (2 * tid + 1 < nn) { off[n0 + 2 * tid + 1] = e0 + excl + a0; degL[2 * tid + 1] = e0 + excl + a0; }
    if (b == NBKT - 1 && tid == 0) off[N] = e1;
    __syncthreads();
    for (int i = e0 + tid; i < e1; i += 256) {
        unsigned p = ebuf[i];
        int dl = (int)(p >> 17);
        int pos = atomicAdd(&degL[dl], 1);
        srcs[pos] = (int)(p & 0x1FFFFu);
    }
}

// ---------------- weight pre-pack (all 6 matrices, one launch) ----------------

struct W6 { const float* w[6]; };

__global__ __launch_bounds__(256) void k_packw6(W6 ws6, ushort* __restrict__ pk) {
    int m = blockIdx.x >> 6;
    int p = (blockIdx.x & 63) * 256 + threadIdx.x;
    const float* W = ws6.w[m];
    ushort* o = pk + (size_t)m * 32768;
    int j = p & 7, l = (p >> 3) & 63, n = (p >> 9) & 7, kc = p >> 12;
    int row = kc * 32 + ((l >> 4) & 3) * 8 + j;
    int col = n * 16 + (l & 15);
    float wv = W[row * 128 + col];
    ushort hi = f2bf(wv);
    ushort lo = f2bf(wv - bf2f(hi));
    o[p] = hi;
    o[16384 + p] = lo;
}

// ---------------- aggregation from fp16 features (+ lazy BN/ReLU): T = f(X[i]) + sum f(X[src]) ----------------
// 4 nodes per wave, 16 lanes/node, 16B (8 ch) per lane, unroll 8

template <bool HASBN>
__global__ __launch_bounds__(256) void k_agg_h(const __half* __restrict__ Xh, float* __restrict__ T,
        const int* __restrict__ off, const int* __restrict__ srcs,
        const float* __restrict__ stats, const float* __restrict__ gamma, const float* __restrict__ beta,
        int N) {
    int gid = blockIdx.x * 256 + threadIdx.x;
    int w = gid >> 6;
    int lane = threadIdx.x & 63;
    int q = lane >> 4;
    int lc = lane & 15;          // channels lc*8 .. lc*8+7
    int node = w * 4 + q;
    if (node >= N) return;

    float g[8], b[8];
    if (HASBN) {
        float invN = 1.0f / (float)N;
        float4 m1a = ((const float4*)stats)[lc * 2];
        float4 m1b = ((const float4*)stats)[lc * 2 + 1];
        float4 m2a = ((const float4*)stats)[32 + lc * 2];
        float4 m2b = ((const float4*)stats)[32 + lc * 2 + 1];
        float4 ga = ((const float4*)gamma)[lc * 2];
        float4 gb = ((const float4*)gamma)[lc * 2 + 1];
        float4 ba = ((const float4*)beta)[lc * 2];
        float4 bb = ((const float4*)beta)[lc * 2 + 1];
        float m1[8] = {m1a.x, m1a.y, m1a.z, m1a.w, m1b.x, m1b.y, m1b.z, m1b.w};
        float m2[8] = {m2a.x, m2a.y, m2a.z, m2a.w, m2b.x, m2b.y, m2b.z, m2b.w};
        float gm[8] = {ga.x, ga.y, ga.z, ga.w, gb.x, gb.y, gb.z, gb.w};
        float bt[8] = {ba.x, ba.y, ba.z, ba.w, bb.x, bb.y, bb.z, bb.w};
#pragma unroll
        for (int t = 0; t < 8; ++t) {
            float mean = m1[t] * invN;
            float var = m2[t] * invN - mean * mean;
            float r = rsqrtf(var + BN_EPS);
            g[t] = gm[t] * r;
            b[t] = bt[t] - mean * g[t];
        }
    }

    const uint4* X16 = (const uint4*)Xh;   // one uint4 = 8 halves; row = 16 uint4
    float acc[8];
    union { uint4 u4; __half h[8]; } cv;

    auto addrow = [&](uint4 raw) {
        union { uint4 u4; __half h[8]; } c2;
        c2.u4 = raw;
#pragma unroll
        for (int t = 0; t < 8; ++t) {
            float v = __half2float(c2.h[t]);
            if (HASBN) v = fmaxf(fmaf(v, g[t], b[t]), 0.f);
            acc[t] += v;
        }
    };

    cv.u4 = X16[(size_t)node * 16 + lc];
#pragma unroll
    for (int t = 0; t < 8; ++t) {
        float v = __half2float(cv.h[t]);
        if (HASBN) v = fmaxf(fmaf(v, g[t], b[t]), 0.f);
        acc[t] = v;
    }

    int s = off[node], e = off[node + 1];
    int j = s;
    for (; j + 7 < e; j += 8) {
        int u0 = srcs[j], u1 = srcs[j + 1], u2 = srcs[j + 2], u3 = srcs[j + 3];
        int u4 = srcs[j + 4], u5 = srcs[j + 5], u6 = srcs[j + 6], u7 = srcs[j + 7];
        uint4 r0 = X16[(size_t)u0 * 16 + lc];
        uint4 r1 = X16[(size_t)u1 * 16 + lc];
        uint4 r2 = X16[(size_t)u2 * 16 + lc];
        uint4 r3 = X16[(size_t)u3 * 16 + lc];
        uint4 r4 = X16[(size_t)u4 * 16 + lc];
        uint4 r5 = X16[(size_t)u5 * 16 + lc];
        uint4 r6 = X16[(size_t)u6 * 16 + lc];
        uint4 r7 = X16[(size_t)u7 * 16 + lc];
        addrow(r0); addrow(r1); addrow(r2); addrow(r3);
        addrow(r4); addrow(r5); addrow(r6); addrow(r7);
    }
    for (; j < e; ++j) addrow(X16[(size_t)srcs[j] * 16 + lc]);

    float4 o0 = make_float4(acc[0], acc[1], acc[2], acc[3]);
    float4 o1 = make_float4(acc[4], acc[5], acc[6], acc[7]);
    ((float4*)T)[(size_t)node * 32 + lc * 2] = o0;
    ((float4*)T)[(size_t)node * 32 + lc * 2 + 1] = o1;
}

// ---------------- fused MLP pair: GEMM1 + ReLU -> LDS restage -> GEMM2 + stats; h out fp16 ----------------

__global__ __launch_bounds__(256, 2) void k_mlp_pair(const float* __restrict__ A, __half* __restrict__ out,
        const ushort* __restrict__ pk1, const float* __restrict__ b1,
        const ushort* __restrict__ pk2, const float* __restrict__ b2,
        float* __restrict__ stats, int N) {
    __shared__ float tile[4 * 32 * 128];   // 64 KB
    int tid = threadIdx.x;
    int wid = tid >> 6, l = tid & 63;
    int lr = l & 15, lg = l >> 4;
    int r0 = blockIdx.x * 128 + wid * 32;
    int wbase = wid * 32 * 128;

    const f32x4* A4 = (const f32x4*)A;
    const s16x8* B1 = (const s16x8*)pk1;
    const s16x8* B2 = (const s16x8*)pk2;

    f32x4 acc[2][8];
#pragma unroll
    for (int m = 0; m < 2; ++m)
#pragma unroll
        for (int n = 0; n < 8; ++n) acc[m][n] = (f32x4){0.f, 0.f, 0.f, 0.f};

    // ---- GEMM1 (A from global) ----
#pragma unroll
    for (int kc = 0; kc < 4; ++kc) {
        s16x8 ahi[2], alo[2];
#pragma unroll
        for (int m = 0; m < 2; ++m) {
            int row = min(r0 + m * 16 + lr, N - 1);
            f32x4 v0 = A4[(size_t)row * 32 + kc * 8 + lg * 2];
            f32x4 v1 = A4[(size_t)row * 32 + kc * 8 + lg * 2 + 1];
            float f[8] = {v0.x, v0.y, v0.z, v0.w, v1.x, v1.y, v1.z, v1.w};
#pragma unroll
            for (int j = 0; j < 8; ++j) {
                ushort hi = f2bf(f[j]);
                ahi[m][j] = (short)hi;
                alo[m][j] = (short)f2bf(f[j] - bf2f(hi));
            }
        }
#pragma unroll
        for (int n = 0; n < 8; ++n) {
            int fi = (kc * 8 + n) * 64 + l;
            s16x8 bhi = B1[fi];
            s16x8 blo = B1[2048 + fi];
#pragma unroll
            for (int m = 0; m < 2; ++m) {
                acc[m][n] = __builtin_amdgcn_mfma_f32_16x16x32_bf16(ahi[m], bhi, acc[m][n], 0, 0, 0);
                acc[m][n] = __builtin_amdgcn_mfma_f32_16x16x32_bf16(alo[m], bhi, acc[m][n], 0, 0, 0);
                acc[m][n] = __builtin_amdgcn_mfma_f32_16x16x32_bf16(ahi[m], blo, acc[m][n], 0, 0, 0);
            }
        }
    }

    // ---- epilogue1: bias + ReLU, restage to LDS (swizzled) ----
#pragma unroll
    for (int n = 0; n < 8; ++n) {
        float bv = b1[n * 16 + lr];
        int c4 = n * 4 + (lr >> 2);
        int e = lr & 3;
#pragma unroll
        for (int m = 0; m < 2; ++m) {
#pragma unroll
            for (int i = 0; i < 4; ++i) {
                int row = m * 16 + lg * 4 + i;
                float v = fmaxf(acc[m][n][i] + bv, 0.f);
                tile[wbase + row * 128 + ((c4 ^ (row & 7)) << 2) + e] = v;
            }
        }
    }
    __syncthreads();

    // ---- GEMM2 (A from LDS) ----
#pragma unroll
    for (int m = 0; m < 2; ++m)
#pragma unroll
        for (int n = 0; n < 8; ++n) acc[m][n] = (f32x4){0.f, 0.f, 0.f, 0.f};

#pragma unroll
    for (int kc = 0; kc < 4; ++kc) {
        s16x8 ahi[2], alo[2];
#pragma unroll
        for (int m = 0; m < 2; ++m) {
            int row = m * 16 + lr;
            float f[8];
#pragma unroll
            for (int h = 0; h < 2; ++h) {
                int k4 = kc * 8 + lg * 2 + h;
                f32x4 v = *(const f32x4*)&tile[wbase + row * 128 + ((k4 ^ (row & 7)) << 2)];
                f[h * 4 + 0] = v.x; f[h * 4 + 1] = v.y; f[h * 4 + 2] = v.z; f[h * 4 + 3] = v.w;
            }
#pragma unroll
            for (int j = 0; j < 8; ++j) {
                ushort hi = f2bf(f[j]);
                ahi[m][j] = (short)hi;
                alo[m][j] = (short)f2bf(f[j] - bf2f(hi));
            }
        }
#pragma unroll
        for (int n = 0; n < 8; ++n) {
            int fi = (kc * 8 + n) * 64 + l;
            s16x8 bhi = B2[fi];
            s16x8 blo = B2[2048 + fi];
#pragma unroll
            for (int m = 0; m < 2; ++m) {
                acc[m][n] = __builtin_amdgcn_mfma_f32_16x16x32_bf16(ahi[m], bhi, acc[m][n], 0, 0, 0);
                acc[m][n] = __builtin_amdgcn_mfma_f32_16x16x32_bf16(alo[m], bhi, acc[m][n], 0, 0, 0);
                acc[m][n] = __builtin_amdgcn_mfma_f32_16x16x32_bf16(ahi[m], blo, acc[m][n], 0, 0, 0);
            }
        }
    }
    __syncthreads();

    // ---- epilogue2: bias, stats, fp16 store ----
    float s1[8], s2[8];
#pragma unroll
    for (int n = 0; n < 8; ++n) { s1[n] = 0.f; s2[n] = 0.f; }

#pragma unroll
    for (int n = 0; n < 8; ++n) {
        float bv = b2[n * 16 + lr];
#pragma unroll
        for (int m = 0; m < 2; ++m) {
#pragma unroll
            for (int i = 0; i < 4; ++i) {
                int r = r0 + m * 16 + lg * 4 + i;
                if (r < N) {
                    float v = acc[m][n][i] + bv;
                    s1[n] += v;
                    s2[n] += v * v;
                    out[(size_t)r * 128 + n * 16 + lr] = __float2half(v);
                }
            }
        }
    }

    float* ls = tile;
#pragma unroll
    for (int n = 0; n < 8; ++n) {
        float a = s1[n], b = s2[n];
        a += __shfl_xor(a, 16, 64); a += __shfl_xor(a, 32, 64);
        b += __shfl_xor(b, 16, 64); b += __shfl_xor(b, 32, 64);
        if (lg == 0) {
            ls[wid * 256 + n * 16 + lr] = a;
            ls[wid * 256 + 128 + n * 16 + lr] = b;
        }
    }
    __syncthreads();
    float t = ls[tid] + ls[256 + tid] + ls[512 + tid] + ls[768 + tid];
    atomicAdd(&stats[tid], t);
}

// ---------------- segmented mean-pool accumulate of f(h) from fp16 ----------------

__global__ __launch_bounds__(128) void k_pool(const __half* __restrict__ h, const float* __restrict__ stats,
                                              const float* __restrict__ gamma, const float* __restrict__ beta,
                                              const int* __restrict__ batch, float* __restrict__ pool,
                                              int loff, int N) {
    int c = threadIdx.x;
    const float invN = 1.0f / (float)N;
    float mean = stats[c] * invN;
    float var = stats[128 + c] * invN - mean * mean;
    float rstd = rsqrtf(var + BN_EPS);
    float gsc = gamma[c] * rstd;
    float bs = beta[c] - mean * gsc;

    int r0 = blockIdx.x * 64;
    int r1 = min(r0 + 64, N);
    float acc = 0.f;
    int curg = -1;
    for (int r = r0; r < r1; ++r) {
        float v = __half2float(h[(size_t)r * 128 + c]);
        float hv = fmaxf(fmaf(v, gsc, bs), 0.f);
        int g = batch[r];
        if (g != curg) {
            if (curg >= 0) atomicAdd(&pool[(size_t)curg * 384 + loff + c], acc);
            curg = g;
            acc = hv;
        } else {
            acc += hv;
        }
    }
    if (curg >= 0) atomicAdd(&pool[(size_t)curg * 384 + loff + c], acc);
}

// ---------------- final linear + row L2-normalize ----------------

__global__ __launch_bounds__(128) void k_final(const float* __restrict__ pool, const int* __restrict__ gcnt,
                                               const float* __restrict__ Wl, const float* __restrict__ bl,
                                               float* __restrict__ out) {
    __shared__ float sh[384];
    __shared__ float red[128];
    int g = blockIdx.x;
    int tid = threadIdx.x;
    float inv = 1.0f / fmaxf((float)gcnt[g], 1.0f);
    for (int t = tid; t < 384; t += 128) sh[t] = pool[(size_t)g * 384 + t] * inv;
    __syncthreads();
    float acc = bl[tid];
    for (int k = 0; k < 384; ++k) acc = fmaf(sh[k], Wl[(size_t)k * 128 + tid], acc);
    red[tid] = acc * acc;
    __syncthreads();
    for (int s = 64; s > 0; s >>= 1) {
        if (tid < s) red[tid] += red[tid + s];
        __syncthreads();
    }
    float norm = sqrtf(red[0]);
    float scale = 1.0f / fmaxf(norm, 1e-12f);
    out[(size_t)g * 128 + tid] = acc * scale;
}

// ---------------- host ----------------

extern "C" void kernel_launch(void* const* d_in, const int* in_sizes, int n_in,
                              void* d_out, int out_size, void* d_ws, size_t ws_size,
                              hipStream_t stream) {
    const float* x = (const float*)d_in[0];
    const int* edge_index = (const int*)d_in[1];
    const int* batch = (const int*)d_in[2];
    const float* Wa[3] = {(const float*)d_in[3], (const float*)d_in[9], (const float*)d_in[15]};
    const float* ba[3] = {(const float*)d_in[4], (const float*)d_in[10], (const float*)d_in[16]};
    const float* Wb[3] = {(const float*)d_in[5], (const float*)d_in[11], (const float*)d_in[17]};
    const float* bb[3] = {(const float*)d_in[6], (const float*)d_in[12], (const float*)d_in[18]};
    const float* gm[3] = {(const float*)d_in[7], (const float*)d_in[13], (const float*)d_in[19]};
    const float* be[3] = {(const float*)d_in[8], (const float*)d_in[14], (const float*)d_in[20]};
    const float* Wl = (const float*)d_in[21];
    const float* bl = (const float*)d_in[22];
    float* out = (float*)d_out;

    const int N = N_NODES, E = N_EDGES, G = N_GRAPHS;
    const int* e_src = edge_index;
    const int* e_dst = edge_index + E;

    char* ws = (char*)d_ws;
    size_t o = 0;
    auto alloc = [&](size_t bytes) -> char* {
        char* p = ws + o;
        o = (o + bytes + 255) & ~(size_t)255;
        return p;
    };
    int* off = (int*)alloc((size_t)(N + 1) * 4);
    int* srcs = (int*)alloc((size_t)E * 4);
    int* gcnt = (int*)alloc((size_t)G * 4);
    int* bcnt = (int*)alloc(256 * 4);
    int* bbase = (int*)alloc(256 * 4);
    int* gcur = (int*)alloc(256 * 4);
    float* stats = (float*)alloc(3 * 256 * 4);
    ushort* wpk = (ushort*)alloc(6 * 32768 * 2);
    float* pool = (float*)alloc((size_t)G * 384 * 4);
    float* T = (float*)alloc((size_t)N * 128 * 4);          // fp32 GIN-sum buffer
    __half* Ha = (__half*)alloc((size_t)N * 128 * 2);       // fp16 feature buffers
    __half* Hb = (__half*)alloc((size_t)N * 128 * 2);
    unsigned* ebuf = (unsigned*)T;   // ebuf dead before T's first write (layer-1 agg)
    (void)ws_size;

    hipMemsetAsync(bcnt, 0, 256 * 4, stream);
    hipMemsetAsync(stats, 0, 3 * 256 * 4, stream);
    hipMemsetAsync(pool, 0, (size_t)G * 384 * 4, stream);

    const int E4 = E / 4;

    k_bcnt<<<256, 256, 0, stream>>>((const int4*)e_dst, bcnt, E4);
    k_bscan<<<1, 256, 0, stream>>>(bcnt, bbase, gcur);
    k_gstart<<<2, 256, 0, stream>>>(batch, gcnt, N);
    k_part<<<(E + PART_CHUNK - 1) / PART_CHUNK, 256, 0, stream>>>(e_src, e_dst, gcur, ebuf, E);
    k_bucket<<<NBKT, 256, 0, stream>>>(ebuf, bbase, off, srcs, N);

    const int n8 = N * 128 / 8;
    k_x2h<<<(n8 + 255) / 256, 256, 0, stream>>>((const float4*)x, (uint4*)Ha, n8);

    W6 w6;
    w6.w[0] = Wa[0]; w6.w[1] = Wb[0]; w6.w[2] = Wa[1];
    w6.w[3] = Wb[1]; w6.w[4] = Wa[2]; w6.w[5] = Wb[2];
    k_packw6<<<384, 256, 0, stream>>>(w6, wpk);

    const int aggBlocks = ((N + 3) / 4 * 64 + 255) / 256;
    const int mlpBlocks = (N + 127) / 128;
    const int poolBlocks = (N + 63) / 64;

    __half* hin[3] = {Ha, Hb, Ha};
    __half* hout[3] = {Hb, Ha, Hb};
    for (int l = 0; l < 3; ++l) {
        float* statsl = stats + l * 256;
        if (l == 0)
            k_agg_h<false><<<aggBlocks, 256, 0, stream>>>(hin[l], T, off, srcs, nullptr, nullptr, nullptr, N);
        else
            k_agg_h<true><<<aggBlocks, 256, 0, stream>>>(hin[l], T, off, srcs, stats + (l - 1) * 256,
                                                         gm[l - 1], be[l - 1], N);
        k_mlp_pair<<<mlpBlocks, 256, 0, stream>>>(T, hout[l], wpk + (size_t)(2 * l) * 32768, ba[l],
                                                  wpk + (size_t)(2 * l + 1) * 32768, bb[l], statsl, N);
        k_pool<<<poolBlocks, 128, 0, stream>>>(hout[l], statsl, gm[l], be[l], batch, pool, l * 128, N);
    }

    k_final<<<G, 128, 0, stream>>>(pool, gcnt, Wl, bl, out);
}